// Round 1
// baseline (7507.266 us; speedup 1.0000x reference)
//
#include <hip/hip_runtime.h>
#include <math.h>

#define N_NODES 20000
#define T_SEQ   8
#define DS      16
#define DD      8
#define E_EDGES 320000
#define HL      128
#define GH      4
#define GC      128
#define HC      512
#define EMB     64
#define IN1     (DS + HL)     // 144
#define KLSTM   (DD + HL)     // 136
#define EP      (E_EDGES + N_NODES)  // 340000 edges incl self loops

// ---------------------------------------------------------------------------
// Generic tiled fp32 GEMM: C[M,Nc] = A[M,K] @ W[Nc,K]^T (+bias)
// BM=BN=128, BK=8, 256 threads, 8x8 per thread. K must be divisible by 8 and
// A/W rows 16B-aligned (K % 4 == 0) — true for K in {136,144,512}.
// ---------------------------------------------------------------------------
#define BM 128
#define BNT 128
#define BK 8

__global__ __launch_bounds__(256) void gemm_bt(
    const float* __restrict__ A, int lda,
    const float* __restrict__ W, int ldw,
    const float* __restrict__ bias,
    float* __restrict__ C, int ldc,
    int M, int Nc, int K)
{
  __shared__ float As[BK * 130];
  __shared__ float Bs[BK * 130];
  const int tid = threadIdx.x;
  const int tx = tid & 15, ty = tid >> 4;
  const int bm = blockIdx.y * BM, bn = blockIdx.x * BNT;

  const int lm = tid >> 1;          // 0..127 row/col within tile
  const int lk = (tid & 1) * 4;     // 0 or 4

  float acc[8][8];
#pragma unroll
  for (int i = 0; i < 8; ++i)
#pragma unroll
    for (int j = 0; j < 8; ++j) acc[i][j] = 0.f;

  for (int k0 = 0; k0 < K; k0 += BK) {
    float4 av = make_float4(0.f, 0.f, 0.f, 0.f);
    const int gm = bm + lm;
    if (gm < M) av = *(const float4*)(A + (size_t)gm * lda + k0 + lk);
    As[(lk + 0) * 130 + lm] = av.x;
    As[(lk + 1) * 130 + lm] = av.y;
    As[(lk + 2) * 130 + lm] = av.z;
    As[(lk + 3) * 130 + lm] = av.w;

    float4 bv = make_float4(0.f, 0.f, 0.f, 0.f);
    const int gn = bn + lm;
    if (gn < Nc) bv = *(const float4*)(W + (size_t)gn * ldw + k0 + lk);
    Bs[(lk + 0) * 130 + lm] = bv.x;
    Bs[(lk + 1) * 130 + lm] = bv.y;
    Bs[(lk + 2) * 130 + lm] = bv.z;
    Bs[(lk + 3) * 130 + lm] = bv.w;
    __syncthreads();

#pragma unroll
    for (int k = 0; k < BK; ++k) {
      float a[8], b[8];
#pragma unroll
      for (int ii = 0; ii < 4; ++ii) {
        float2 t = *(const float2*)&As[k * 130 + ty * 2 + 32 * ii];
        a[2 * ii] = t.x; a[2 * ii + 1] = t.y;
      }
#pragma unroll
      for (int jj = 0; jj < 4; ++jj) {
        float2 t = *(const float2*)&Bs[k * 130 + tx * 2 + 32 * jj];
        b[2 * jj] = t.x; b[2 * jj + 1] = t.y;
      }
#pragma unroll
      for (int i = 0; i < 8; ++i)
#pragma unroll
        for (int j = 0; j < 8; ++j)
          acc[i][j] = fmaf(a[i], b[j], acc[i][j]);
    }
    __syncthreads();
  }

#pragma unroll
  for (int i = 0; i < 8; ++i) {
    const int m = bm + ty * 2 + 32 * (i >> 1) + (i & 1);
    if (m >= M) continue;
#pragma unroll
    for (int j = 0; j < 8; ++j) {
      const int n = bn + tx * 2 + 32 * (j >> 1) + (j & 1);
      if (n >= Nc) continue;
      float v = acc[i][j];
      if (bias) v += bias[n];
      C[(size_t)m * ldc + n] = v;
    }
  }
}

// ---------------------------------------------------------------------------
// Small helper kernels
// ---------------------------------------------------------------------------
__global__ void k_bias_sum(const float* __restrict__ b_ih,
                           const float* __restrict__ b_hh,
                           float* __restrict__ bsum) {
  int i = blockIdx.x * blockDim.x + threadIdx.x;
  if (i < 4 * HL) bsum[i] = b_ih[i] + b_hh[i];
}

__global__ void k_wcat(const float* __restrict__ W_ih,
                       const float* __restrict__ W_hh,
                       float* __restrict__ wcat) {
  int idx = blockIdx.x * blockDim.x + threadIdx.x;
  if (idx >= 4 * HL * KLSTM) return;
  int j = idx / KLSTM, k = idx - j * KLSTM;
  wcat[idx] = (k < DD) ? W_ih[j * DD + k] : W_hh[j * HL + (k - DD)];
}

__global__ void pack_xh(const float* __restrict__ dyn,
                        const float* __restrict__ h,
                        float* __restrict__ pack, int t) {
  int idx = blockIdx.x * blockDim.x + threadIdx.x;
  if (idx >= N_NODES * KLSTM) return;
  int n = idx / KLSTM, k = idx - n * KLSTM;
  pack[idx] = (k < DD) ? dyn[(size_t)n * (T_SEQ * DD) + t * DD + k]
                       : h[(size_t)n * HL + (k - DD)];
}

__global__ void pack_g1(const float* __restrict__ xs,
                        const float* __restrict__ h,
                        float* __restrict__ pack) {
  int idx = blockIdx.x * blockDim.x + threadIdx.x;
  if (idx >= N_NODES * IN1) return;
  int n = idx / IN1, k = idx - n * IN1;
  pack[idx] = (k < DS) ? xs[n * DS + k] : h[(size_t)n * HL + (k - DS)];
}

__global__ void lstm_update(const float* __restrict__ gates,
                            float* __restrict__ h, float* __restrict__ c) {
  int idx = blockIdx.x * blockDim.x + threadIdx.x;
  if (idx >= N_NODES * HL) return;
  int n = idx >> 7, j = idx & 127;
  const float* g = gates + (size_t)n * (4 * HL);
  float gi = g[j], gf = g[j + 128], gg = g[j + 256], go = g[j + 384];
  float si = 1.f / (1.f + __expf(-gi));
  float sf = 1.f / (1.f + __expf(-gf));
  float so = 1.f / (1.f + __expf(-go));
  float cn = sf * c[idx] + si * tanhf(gg);
  c[idx] = cn;
  h[idx] = so * tanhf(cn);
}

// ---------------------------------------------------------------------------
// CSR build (dst-sorted). Rebuilt every launch (ws is re-poisoned).
// ---------------------------------------------------------------------------
__global__ void k_deg(const int* __restrict__ ei, int* __restrict__ deg) {
  int e = blockIdx.x * blockDim.x + threadIdx.x;
  if (e >= EP) return;
  int d = (e < E_EDGES) ? ei[E_EDGES + e] : (e - E_EDGES);
  atomicAdd(&deg[d], 1);
}

__global__ __launch_bounds__(1024) void k_scan(const int* __restrict__ deg,
                                               int* __restrict__ rowstart) {
  __shared__ int buf[1024];
  __shared__ int carry_s;
  const int tid = threadIdx.x;
  if (tid == 0) carry_s = 0;
  __syncthreads();
  for (int base = 0; base < N_NODES; base += 1024) {
    int v = (base + tid < N_NODES) ? deg[base + tid] : 0;
    buf[tid] = v;
    __syncthreads();
    for (int off = 1; off < 1024; off <<= 1) {
      int add = (tid >= off) ? buf[tid - off] : 0;
      __syncthreads();
      buf[tid] += add;
      __syncthreads();
    }
    int incl = buf[tid];
    int carry = carry_s;
    if (base + tid < N_NODES) rowstart[base + tid] = carry + incl - v;
    __syncthreads();
    if (tid == 1023) carry_s = carry + incl;
    __syncthreads();
  }
  if (tid == 0) rowstart[N_NODES] = carry_s;
}

__global__ void k_fill(const int* __restrict__ ei,
                       const int* __restrict__ rowstart,
                       int* __restrict__ cursor, int* __restrict__ csr) {
  int e = blockIdx.x * blockDim.x + threadIdx.x;
  if (e >= EP) return;
  int s, d;
  if (e < E_EDGES) { s = ei[e]; d = ei[E_EDGES + e]; }
  else             { s = d = e - E_EDGES; }
  int pos = atomicAdd(&cursor[d], 1);
  csr[rowstart[d] + pos] = s;
}

// ---------------------------------------------------------------------------
// GATv2 edge softmax + aggregation. One block per dst node, one wave per head,
// lane handles 2 channels. Online softmax => single pass over edges, no
// atomics, numerics equivalent to segment_max/segment_sum reference.
// ---------------------------------------------------------------------------
__global__ __launch_bounds__(256) void gat_edge(
    const float* __restrict__ xl, const float* __restrict__ xr,
    const float* __restrict__ att, const float* __restrict__ bias,
    const int* __restrict__ rowstart, const int* __restrict__ csr,
    float* __restrict__ out)
{
  const int d = blockIdx.x;
  const int wv = threadIdx.x >> 6;       // head
  const int lane = threadIdx.x & 63;
  const int ch = wv * GC + lane * 2;     // channel pair within [0,512)
  const float2 rx = *(const float2*)(xr + (size_t)d * HC + ch);
  const float2 av = *(const float2*)(att + ch);
  const int row = rowstart[d], end = rowstart[d + 1];

  float m = -INFINITY, l = 0.f, a0 = 0.f, a1 = 0.f;
  for (int i = row; i < end; ++i) {
    const int s = csr[i];
    const float2 xv = *(const float2*)(xl + (size_t)s * HC + ch);
    float e0 = xv.x + rx.x; e0 = e0 > 0.f ? e0 : 0.2f * e0;
    float e1 = xv.y + rx.y; e1 = e1 > 0.f ? e1 : 0.2f * e1;
    float p = e0 * av.x + e1 * av.y;
#pragma unroll
    for (int off = 1; off < 64; off <<= 1) p += __shfl_xor(p, off);
    const float nm = fmaxf(m, p);
    const float sc = __expf(m - nm);   // m=-inf on first iter -> 0
    const float w  = __expf(p - nm);
    l  = l * sc + w;
    a0 = a0 * sc + w * xv.x;
    a1 = a1 * sc + w * xv.y;
    m = nm;
  }
  const float inv = 1.f / l;
  const size_t ob = (size_t)d * HC + ch;
  out[ob]     = a0 * inv + bias[ch];
  out[ob + 1] = a1 * inv + bias[ch + 1];
}

// ---------------------------------------------------------------------------
// BatchNorm (eval-style batch stats, biased var) + ReLU
// ---------------------------------------------------------------------------
__global__ __launch_bounds__(256) void bn_stats(const float* __restrict__ x,
                                                float* __restrict__ stats) {
  const int tid = threadIdx.x;
  const int c0 = tid, c1 = tid + 256;
  const int rows_per = (N_NODES + gridDim.x - 1) / gridDim.x;
  const int r0 = blockIdx.x * rows_per;
  const int r1 = min(r0 + rows_per, N_NODES);
  float s0 = 0.f, s1 = 0.f, q0 = 0.f, q1 = 0.f;
  for (int r = r0; r < r1; ++r) {
    const float v0 = x[(size_t)r * HC + c0];
    const float v1 = x[(size_t)r * HC + c1];
    s0 += v0; q0 += v0 * v0;
    s1 += v1; q1 += v1 * v1;
  }
  atomicAdd(&stats[c0], s0);
  atomicAdd(&stats[c1], s1);
  atomicAdd(&stats[HC + c0], q0);
  atomicAdd(&stats[HC + c1], q1);
}

__global__ void bn_apply(float* __restrict__ x, const float* __restrict__ stats,
                         const float* __restrict__ gamma,
                         const float* __restrict__ beta) {
  int idx = blockIdx.x * blockDim.x + threadIdx.x;
  if (idx >= N_NODES * HC) return;
  const int cc = idx & (HC - 1);
  const float mean = stats[cc] * (1.f / N_NODES);
  const float var  = stats[HC + cc] * (1.f / N_NODES) - mean * mean;
  const float inv  = rsqrtf(var + 1e-5f);
  float z = (x[idx] - mean) * inv * gamma[cc] + beta[cc];
  x[idx] = z > 0.f ? z : 0.f;
}

// ---------------------------------------------------------------------------
extern "C" void kernel_launch(void* const* d_in, const int* in_sizes, int n_in,
                              void* d_out, int out_size, void* d_ws, size_t ws_size,
                              hipStream_t stream) {
  const float* x_static = (const float*)d_in[0];
  const float* dyn      = (const float*)d_in[1];
  const int*   ei       = (const int*)d_in[2];
  const float* W_ih     = (const float*)d_in[3];
  const float* W_hh     = (const float*)d_in[4];
  const float* b_ih     = (const float*)d_in[5];
  const float* b_hh     = (const float*)d_in[6];
  const float* Wl1      = (const float*)d_in[7];
  const float* Wr1      = (const float*)d_in[8];
  const float* att1     = (const float*)d_in[9];
  const float* bg1      = (const float*)d_in[10];
  const float* Wl2      = (const float*)d_in[11];
  const float* Wr2      = (const float*)d_in[12];
  const float* att2     = (const float*)d_in[13];
  const float* bg2      = (const float*)d_in[14];
  const float* gamma1   = (const float*)d_in[15];
  const float* beta1    = (const float*)d_in[16];
  const float* gamma2   = (const float*)d_in[17];
  const float* beta2    = (const float*)d_in[18];
  const float* Wp       = (const float*)d_in[19];
  const float* bp       = (const float*)d_in[20];
  float* out = (float*)d_out;

  float* ws = (float*)d_ws;
  size_t o = 0;
  float* h     = ws + o; o += (size_t)N_NODES * HL;
  float* cst   = ws + o; o += (size_t)N_NODES * HL;
  float* pack  = ws + o; o += (size_t)N_NODES * IN1;
  float* gates = ws + o; o += (size_t)N_NODES * HC;   // also reused as agg2
  float* xl    = ws + o; o += (size_t)N_NODES * HC;
  float* xr    = ws + o; o += (size_t)N_NODES * HC;
  float* agg   = ws + o; o += (size_t)N_NODES * HC;
  float* stats = ws + o; o += 2 * HC;
  float* bsum  = ws + o; o += 4 * HL;
  float* wcat  = ws + o; o += (size_t)4 * HL * KLSTM;
  int* deg      = (int*)(ws + o); o += N_NODES;
  int* cursor   = (int*)(ws + o); o += N_NODES;
  int* rowstart = (int*)(ws + o); o += N_NODES + 64;
  int* csr      = (int*)(ws + o); o += EP;

  // ---- per-launch init (ws is poisoned before every timed call) ----
  hipMemsetAsync(deg,    0, N_NODES * sizeof(int), stream);
  hipMemsetAsync(cursor, 0, N_NODES * sizeof(int), stream);
  hipMemsetAsync(h,   0, (size_t)N_NODES * HL * sizeof(float), stream);
  hipMemsetAsync(cst, 0, (size_t)N_NODES * HL * sizeof(float), stream);

  k_bias_sum<<<2, 256, 0, stream>>>(b_ih, b_hh, bsum);
  k_wcat<<<(4 * HL * KLSTM + 255) / 256, 256, 0, stream>>>(W_ih, W_hh, wcat);
  k_deg<<<(EP + 255) / 256, 256, 0, stream>>>(ei, deg);
  k_scan<<<1, 1024, 0, stream>>>(deg, rowstart);
  k_fill<<<(EP + 255) / 256, 256, 0, stream>>>(ei, rowstart, cursor, csr);

  const dim3 gemm_grid_512((HC + BNT - 1) / BNT, (N_NODES + BM - 1) / BM);     // (4,157)
  const dim3 gemm_grid_emb((EMB + BNT - 1) / BNT, (N_NODES + BM - 1) / BM);    // (1,157)

  for (int t = 0; t < T_SEQ; ++t) {
    // ---- LSTM step t ----
    pack_xh<<<(N_NODES * KLSTM + 255) / 256, 256, 0, stream>>>(dyn, h, pack, t);
    gemm_bt<<<gemm_grid_512, 256, 0, stream>>>(pack, KLSTM, wcat, KLSTM, bsum,
                                               gates, HC, N_NODES, HC, KLSTM);
    lstm_update<<<(N_NODES * HL + 255) / 256, 256, 0, stream>>>(gates, h, cst);

    // ---- GAT layer 1 ----
    pack_g1<<<(N_NODES * IN1 + 255) / 256, 256, 0, stream>>>(x_static, h, pack);
    gemm_bt<<<gemm_grid_512, 256, 0, stream>>>(pack, IN1, Wl1, IN1, nullptr,
                                               xl, HC, N_NODES, HC, IN1);
    gemm_bt<<<gemm_grid_512, 256, 0, stream>>>(pack, IN1, Wr1, IN1, nullptr,
                                               xr, HC, N_NODES, HC, IN1);
    gat_edge<<<N_NODES, 256, 0, stream>>>(xl, xr, att1, bg1, rowstart, csr, agg);
    hipMemsetAsync(stats, 0, 2 * HC * sizeof(float), stream);
    bn_stats<<<160, 256, 0, stream>>>(agg, stats);
    bn_apply<<<(N_NODES * HC + 255) / 256, 256, 0, stream>>>(agg, stats, gamma1, beta1);

    // ---- GAT layer 2 ----
    gemm_bt<<<gemm_grid_512, 256, 0, stream>>>(agg, HC, Wl2, HC, nullptr,
                                               xl, HC, N_NODES, HC, HC);
    gemm_bt<<<gemm_grid_512, 256, 0, stream>>>(agg, HC, Wr2, HC, nullptr,
                                               xr, HC, N_NODES, HC, HC);
    gat_edge<<<N_NODES, 256, 0, stream>>>(xl, xr, att2, bg2, rowstart, csr, gates);
    hipMemsetAsync(stats, 0, 2 * HC * sizeof(float), stream);
    bn_stats<<<160, 256, 0, stream>>>(gates, stats);
    bn_apply<<<(N_NODES * HC + 255) / 256, 256, 0, stream>>>(gates, stats, gamma2, beta2);

    // ---- output projection into out[n][t][:] ----
    gemm_bt<<<gemm_grid_emb, 256, 0, stream>>>(gates, HC, Wp, HC, bp,
                                               out + t * EMB, T_SEQ * EMB,
                                               N_NODES, EMB, HC);
  }
}

// Round 2
// 4276.262 us; speedup vs baseline: 1.7556x; 1.7556x over previous
//
#include <hip/hip_runtime.h>
#include <math.h>

typedef unsigned short u16;
typedef unsigned int u32;

#define N_NODES 20000
#define MP      20096            // N padded to multiple of 128
#define T_SEQ   8
#define DS      16
#define DD      8
#define E_EDGES 320000
#define HL      128
#define GH      4
#define GC      128
#define HC      512
#define EMB     64
#define KP1     160              // padded K for LSTM (136) and GAT1 (144)
#define EP      (E_EDGES + N_NODES)

typedef __attribute__((ext_vector_type(8))) short bf16x8;
typedef __attribute__((ext_vector_type(4))) float f32x4;

__device__ __forceinline__ u16 f2bf(float f) {
  u32 u = __float_as_uint(f);
  u += 0x7fff + ((u >> 16) & 1);   // RNE (inputs are finite)
  return (u16)(u >> 16);
}

__device__ __forceinline__ void gld16(const void* g, void* l) {
  __builtin_amdgcn_global_load_lds(
      (const __attribute__((address_space(1))) void*)g,
      (__attribute__((address_space(3))) void*)l, 16, 0, 0);
}

// ---------------------------------------------------------------------------
// bf16 MFMA GEMM: C[M,Nc] = A[M,K] @ W[Nc,K]^T (+bias).
// A: bf16 [>=gridY*128, K], W: bf16 [Nc(ceil), K], K % 32 == 0.
// 128x128 tile, BK=32, 4 waves -> 64x64 each (4x4 of 16x16x32 MFMA).
// global_load_lds width=16 staging (LDS layout = linear row-major [128][32]).
// ---------------------------------------------------------------------------
__global__ __launch_bounds__(256) void gemm_mfma(
    const u16* __restrict__ A, int lda,
    const u16* __restrict__ W, int ldw,
    const float* __restrict__ bias,
    void* __restrict__ Cout, int ldc,
    int M, int Nc, int K, int c_bf16)
{
  __shared__ u16 Asm[128 * 32];
  __shared__ u16 Bsm[128 * 32];
  const int tid = threadIdx.x;
  const int wave = tid >> 6, lane = tid & 63;
  const int wm = (wave >> 1) << 6, wn = (wave & 1) << 6;
  const int bm = blockIdx.y * 128, bn = blockIdx.x * 128;

  f32x4 acc[4][4];
#pragma unroll
  for (int i = 0; i < 4; ++i)
#pragma unroll
    for (int j = 0; j < 4; ++j) acc[i][j] = (f32x4){0.f, 0.f, 0.f, 0.f};

  const int qr = lane >> 2;          // 0..15: row within 16-row chunk
  const int qc = (lane & 3) << 3;    // k-offset in elements (0,8,16,24)
  const int q0 = wave * 2, q1 = wave * 2 + 1;
  const int ra0 = bm + q0 * 16 + qr;          // A rows always physically valid (MP rows)
  const int ra1 = bm + q1 * 16 + qr;
  int rb0 = bn + q0 * 16 + qr; if (rb0 >= Nc) rb0 = Nc - 1;   // clamp (proj Nc=64)
  int rb1 = bn + q1 * 16 + qr; if (rb1 >= Nc) rb1 = Nc - 1;

  const int fm = lane & 15;
  const int fk = (lane >> 4) << 3;

  for (int k0 = 0; k0 < K; k0 += 32) {
    gld16(A + (size_t)ra0 * lda + k0 + qc, &Asm[q0 * 512]);
    gld16(A + (size_t)ra1 * lda + k0 + qc, &Asm[q1 * 512]);
    gld16(W + (size_t)rb0 * ldw + k0 + qc, &Bsm[q0 * 512]);
    gld16(W + (size_t)rb1 * ldw + k0 + qc, &Bsm[q1 * 512]);
    __syncthreads();

    bf16x8 af[4], bfr[4];
#pragma unroll
    for (int i = 0; i < 4; ++i)
      af[i] = *(const bf16x8*)&Asm[(wm + i * 16 + fm) * 32 + fk];
#pragma unroll
    for (int j = 0; j < 4; ++j)
      bfr[j] = *(const bf16x8*)&Bsm[(wn + j * 16 + fm) * 32 + fk];
#pragma unroll
    for (int i = 0; i < 4; ++i)
#pragma unroll
      for (int j = 0; j < 4; ++j)
        acc[i][j] = __builtin_amdgcn_mfma_f32_16x16x32_bf16(af[i], bfr[j], acc[i][j], 0, 0, 0);
    __syncthreads();
  }

  // C/D layout: col = lane&15, row = (lane>>4)*4 + reg
  const int cn = lane & 15, cm = (lane >> 4) << 2;
#pragma unroll
  for (int j = 0; j < 4; ++j) {
    const int c = bn + wn + j * 16 + cn;
    if (c >= Nc) continue;
    const float bb = bias ? bias[c] : 0.f;
#pragma unroll
    for (int i = 0; i < 4; ++i) {
#pragma unroll
      for (int r = 0; r < 4; ++r) {
        const int m = bm + wm + i * 16 + cm + r;
        if (m >= M) continue;
        const float v = acc[i][j][r] + bb;
        if (c_bf16) ((u16*)Cout)[(size_t)m * ldc + c] = f2bf(v);
        else        ((float*)Cout)[(size_t)m * ldc + c] = v;
      }
    }
  }
}

// ---------------------------------------------------------------------------
// Setup / conversion kernels (once per launch; tiny)
// ---------------------------------------------------------------------------
__global__ void k_bias_sum(const float* __restrict__ b_ih,
                           const float* __restrict__ b_hh,
                           float* __restrict__ bsum) {
  int i = blockIdx.x * blockDim.x + threadIdx.x;
  if (i < 4 * HL) bsum[i] = b_ih[i] + b_hh[i];
}

__global__ void k_wcat_bf(const float* __restrict__ W_ih,
                          const float* __restrict__ W_hh,
                          u16* __restrict__ w) {
  int idx = blockIdx.x * blockDim.x + threadIdx.x;
  if (idx >= HC * KP1) return;
  int j = idx / KP1, k = idx - j * KP1;
  float v = 0.f;
  if (k < DD) v = W_ih[j * DD + k];
  else if (k < DD + HL) v = W_hh[j * HL + (k - DD)];
  w[idx] = f2bf(v);
}

__global__ void k_wlr1_bf(const float* __restrict__ Wl,
                          const float* __restrict__ Wr,
                          u16* __restrict__ w) {
  int idx = blockIdx.x * blockDim.x + threadIdx.x;
  if (idx >= 2 * HC * KP1) return;
  int j = idx / KP1, k = idx - j * KP1;
  const float* src = (j < HC) ? Wl : Wr;
  int jj = j & (HC - 1);
  float v = (k < DS + HL) ? src[jj * (DS + HL) + k] : 0.f;
  w[idx] = f2bf(v);
}

__global__ void k_wlr2_bf(const float* __restrict__ Wl,
                          const float* __restrict__ Wr,
                          u16* __restrict__ w) {
  int idx = blockIdx.x * blockDim.x + threadIdx.x;
  if (idx >= 2 * HC * HC) return;
  int j = idx >> 9, k = idx & (HC - 1);
  const float* src = (j < HC) ? Wl : Wr;
  int jj = j & (HC - 1);
  w[idx] = f2bf(src[jj * HC + k]);
}

__global__ void k_wp_bf(const float* __restrict__ Wp, u16* __restrict__ w) {
  int idx = blockIdx.x * blockDim.x + threadIdx.x;
  if (idx < EMB * HC) w[idx] = f2bf(Wp[idx]);
}

// ---------------------------------------------------------------------------
// Packing (fp32 -> bf16, K padded, rows padded to MP with zeros)
// ---------------------------------------------------------------------------
__global__ void pack_xh(const float* __restrict__ dyn,
                        const float* __restrict__ h,
                        u16* __restrict__ pack, int t) {
  int idx = blockIdx.x * blockDim.x + threadIdx.x;
  if (idx >= MP * KP1) return;
  int n = idx / KP1, k = idx - n * KP1;
  float v = 0.f;
  if (n < N_NODES) {
    if (k < DD) v = dyn[(size_t)n * (T_SEQ * DD) + t * DD + k];
    else if (k < DD + HL) v = h[(size_t)n * HL + (k - DD)];
  }
  pack[idx] = f2bf(v);
}

__global__ void pack_g1(const float* __restrict__ xs,
                        const float* __restrict__ h,
                        u16* __restrict__ pack) {
  int idx = blockIdx.x * blockDim.x + threadIdx.x;
  if (idx >= MP * KP1) return;
  int n = idx / KP1, k = idx - n * KP1;
  float v = 0.f;
  if (n < N_NODES) {
    if (k < DS) v = xs[(size_t)n * DS + k];
    else if (k < DS + HL) v = h[(size_t)n * HL + (k - DS)];
  }
  pack[idx] = f2bf(v);
}

__global__ void lstm_update(const float* __restrict__ gates,
                            float* __restrict__ h, float* __restrict__ c) {
  int idx = blockIdx.x * blockDim.x + threadIdx.x;
  if (idx >= N_NODES * HL) return;
  int n = idx >> 7, j = idx & 127;
  const float* g = gates + (size_t)n * HC;
  float gi = g[j], gf = g[j + 128], gg = g[j + 256], go = g[j + 384];
  float si = 1.f / (1.f + __expf(-gi));
  float sf = 1.f / (1.f + __expf(-gf));
  float so = 1.f / (1.f + __expf(-go));
  float cn = sf * c[idx] + si * tanhf(gg);
  c[idx] = cn;
  h[idx] = so * tanhf(cn);
}

// ---------------------------------------------------------------------------
// CSR build (dst-sorted), rebuilt every launch
// ---------------------------------------------------------------------------
__global__ void k_deg(const int* __restrict__ ei, int* __restrict__ deg) {
  int e = blockIdx.x * blockDim.x + threadIdx.x;
  if (e >= EP) return;
  int d = (e < E_EDGES) ? ei[E_EDGES + e] : (e - E_EDGES);
  atomicAdd(&deg[d], 1);
}

__global__ __launch_bounds__(1024) void k_scan(const int* __restrict__ deg,
                                               int* __restrict__ rowstart) {
  __shared__ int buf[1024];
  __shared__ int carry_s;
  const int tid = threadIdx.x;
  if (tid == 0) carry_s = 0;
  __syncthreads();
  for (int base = 0; base < N_NODES; base += 1024) {
    int v = (base + tid < N_NODES) ? deg[base + tid] : 0;
    buf[tid] = v;
    __syncthreads();
    for (int off = 1; off < 1024; off <<= 1) {
      int add = (tid >= off) ? buf[tid - off] : 0;
      __syncthreads();
      buf[tid] += add;
      __syncthreads();
    }
    int incl = buf[tid];
    int carry = carry_s;
    if (base + tid < N_NODES) rowstart[base + tid] = carry + incl - v;
    __syncthreads();
    if (tid == 1023) carry_s = carry + incl;
    __syncthreads();
  }
  if (tid == 0) rowstart[N_NODES] = carry_s;
}

__global__ void k_fill(const int* __restrict__ ei,
                       const int* __restrict__ rowstart,
                       int* __restrict__ cursor, int* __restrict__ csr) {
  int e = blockIdx.x * blockDim.x + threadIdx.x;
  if (e >= EP) return;
  int s, d;
  if (e < E_EDGES) { s = ei[e]; d = ei[E_EDGES + e]; }
  else             { s = d = e - E_EDGES; }
  int pos = atomicAdd(&cursor[d], 1);
  csr[rowstart[d] + pos] = s;
}

// ---------------------------------------------------------------------------
// GATv2 edge softmax + aggregation, xl/xr packed bf16 [MP, 1024]
// (cols 0..511 = xl, 512..1023 = xr). One block per dst, wave per head,
// lane = 2 channels, online softmax -> single pass, no atomics.
// ---------------------------------------------------------------------------
__global__ __launch_bounds__(256) void gat_edge(
    const u16* __restrict__ xlr,
    const float* __restrict__ att, const float* __restrict__ bias,
    const int* __restrict__ rowstart, const int* __restrict__ csr,
    float* __restrict__ out)
{
  const int d = blockIdx.x;
  const int head = threadIdx.x >> 6, lane = threadIdx.x & 63;
  const int ch = head * GC + lane * 2;
  const u32 vr = *(const u32*)(xlr + (size_t)d * 1024 + 512 + ch);
  const float rx0 = __uint_as_float(vr << 16);
  const float rx1 = __uint_as_float(vr & 0xffff0000u);
  const float2 av = *(const float2*)(att + ch);
  const int row = rowstart[d], end = rowstart[d + 1];

  float m = -INFINITY, l = 0.f, a0 = 0.f, a1 = 0.f;
  for (int i = row; i < end; ++i) {
    const int s = csr[i];
    const u32 v = *(const u32*)(xlr + (size_t)s * 1024 + ch);
    const float x0 = __uint_as_float(v << 16);
    const float x1 = __uint_as_float(v & 0xffff0000u);
    float e0 = x0 + rx0; e0 = e0 > 0.f ? e0 : 0.2f * e0;
    float e1 = x1 + rx1; e1 = e1 > 0.f ? e1 : 0.2f * e1;
    float p = fmaf(e0, av.x, e1 * av.y);
#pragma unroll
    for (int off = 1; off < 64; off <<= 1) p += __shfl_xor(p, off);
    const float nm = fmaxf(m, p);
    const float sc = __expf(m - nm);   // first iter: exp(-inf)=0
    const float w  = __expf(p - nm);
    l  = fmaf(l, sc, w);
    a0 = fmaf(a0, sc, w * x0);
    a1 = fmaf(a1, sc, w * x1);
    m = nm;
  }
  const float inv = 1.f / l;
  const size_t ob = (size_t)d * HC + ch;
  out[ob]     = fmaf(a0, inv, bias[ch]);
  out[ob + 1] = fmaf(a1, inv, bias[ch + 1]);
}

// ---------------------------------------------------------------------------
// BatchNorm (batch stats, biased var) + ReLU -> bf16 (pad rows zeroed)
// ---------------------------------------------------------------------------
__global__ __launch_bounds__(256) void bn_stats(const float* __restrict__ x,
                                                float* __restrict__ stats) {
  const int tid = threadIdx.x;
  const int c0 = tid, c1 = tid + 256;
  const int rows_per = (N_NODES + gridDim.x - 1) / gridDim.x;
  const int r0 = blockIdx.x * rows_per;
  const int r1 = min(r0 + rows_per, N_NODES);
  float s0 = 0.f, s1 = 0.f, q0 = 0.f, q1 = 0.f;
  for (int r = r0; r < r1; ++r) {
    const float v0 = x[(size_t)r * HC + c0];
    const float v1 = x[(size_t)r * HC + c1];
    s0 += v0; q0 += v0 * v0;
    s1 += v1; q1 += v1 * v1;
  }
  atomicAdd(&stats[c0], s0);
  atomicAdd(&stats[c1], s1);
  atomicAdd(&stats[HC + c0], q0);
  atomicAdd(&stats[HC + c1], q1);
}

__global__ void bn_apply(const float* __restrict__ x,
                         const float* __restrict__ stats,
                         const float* __restrict__ gamma,
                         const float* __restrict__ beta,
                         u16* __restrict__ outb) {
  int idx = blockIdx.x * blockDim.x + threadIdx.x;
  if (idx >= MP * HC) return;
  const int n = idx >> 9, cc = idx & (HC - 1);
  if (n >= N_NODES) { outb[idx] = 0; return; }
  const float mean = stats[cc] * (1.f / N_NODES);
  const float var  = stats[HC + cc] * (1.f / N_NODES) - mean * mean;
  const float inv  = rsqrtf(var + 1e-5f);
  float z = (x[idx] - mean) * inv * gamma[cc] + beta[cc];
  outb[idx] = f2bf(z > 0.f ? z : 0.f);
}

// ---------------------------------------------------------------------------
extern "C" void kernel_launch(void* const* d_in, const int* in_sizes, int n_in,
                              void* d_out, int out_size, void* d_ws, size_t ws_size,
                              hipStream_t stream) {
  const float* x_static = (const float*)d_in[0];
  const float* dyn      = (const float*)d_in[1];
  const int*   ei       = (const int*)d_in[2];
  const float* W_ih     = (const float*)d_in[3];
  const float* W_hh     = (const float*)d_in[4];
  const float* b_ih     = (const float*)d_in[5];
  const float* b_hh     = (const float*)d_in[6];
  const float* Wl1      = (const float*)d_in[7];
  const float* Wr1      = (const float*)d_in[8];
  const float* att1     = (const float*)d_in[9];
  const float* bg1      = (const float*)d_in[10];
  const float* Wl2      = (const float*)d_in[11];
  const float* Wr2      = (const float*)d_in[12];
  const float* att2     = (const float*)d_in[13];
  const float* bg2      = (const float*)d_in[14];
  const float* gamma1   = (const float*)d_in[15];
  const float* beta1    = (const float*)d_in[16];
  const float* gamma2   = (const float*)d_in[17];
  const float* beta2    = (const float*)d_in[18];
  const float* Wp       = (const float*)d_in[19];
  const float* bp       = (const float*)d_in[20];
  float* out = (float*)d_out;

  // ---- workspace carve (floats) ----
  float* ws = (float*)d_ws;
  size_t o = 0;
  float* h     = ws + o; o += (size_t)MP * HL;
  float* cst   = ws + o; o += (size_t)MP * HL;
  float* agg   = ws + o; o += (size_t)MP * HC;      // fp32: LSTM gates / GAT agg
  float* stats = ws + o; o += 2 * HC;
  float* bsum  = ws + o; o += 4 * HL;
  u16* packA   = (u16*)(ws + o); o += (size_t)MP * KP1 / 2;
  u16* xlr     = (u16*)(ws + o); o += (size_t)MP * 1024 / 2;
  u16* aggb    = (u16*)(ws + o); o += (size_t)MP * HC / 2;
  u16* wcat_bf = (u16*)(ws + o); o += (size_t)HC * KP1 / 2;
  u16* wlr1_bf = (u16*)(ws + o); o += (size_t)2 * HC * KP1 / 2;
  u16* wlr2_bf = (u16*)(ws + o); o += (size_t)2 * HC * HC / 2;
  u16* wp_bf   = (u16*)(ws + o); o += (size_t)EMB * HC / 2;
  int* deg      = (int*)(ws + o); o += N_NODES;
  int* cursor   = (int*)(ws + o); o += N_NODES;
  int* rowstart = (int*)(ws + o); o += N_NODES + 64;
  int* csr      = (int*)(ws + o); o += EP;

  // ---- per-launch init ----
  hipMemsetAsync(deg,    0, N_NODES * sizeof(int), stream);
  hipMemsetAsync(cursor, 0, N_NODES * sizeof(int), stream);
  hipMemsetAsync(h,   0, (size_t)MP * HL * sizeof(float), stream);
  hipMemsetAsync(cst, 0, (size_t)MP * HL * sizeof(float), stream);

  k_bias_sum<<<2, 256, 0, stream>>>(b_ih, b_hh, bsum);
  k_wcat_bf<<<(HC * KP1 + 255) / 256, 256, 0, stream>>>(W_ih, W_hh, wcat_bf);
  k_wlr1_bf<<<(2 * HC * KP1 + 255) / 256, 256, 0, stream>>>(Wl1, Wr1, wlr1_bf);
  k_wlr2_bf<<<(2 * HC * HC + 255) / 256, 256, 0, stream>>>(Wl2, Wr2, wlr2_bf);
  k_wp_bf<<<(EMB * HC + 255) / 256, 256, 0, stream>>>(Wp, wp_bf);
  k_deg<<<(EP + 255) / 256, 256, 0, stream>>>(ei, deg);
  k_scan<<<1, 1024, 0, stream>>>(deg, rowstart);
  k_fill<<<(EP + 255) / 256, 256, 0, stream>>>(ei, rowstart, cursor, csr);

  const int GY = MP / 128;                       // 157
  const dim3 g_gates(HC / 128, GY);              // (4,157)
  const dim3 g_xlr(2 * HC / 128, GY);            // (8,157)
  const dim3 g_proj(1, GY);                      // (1,157)
  const int PK = (MP * KP1 + 255) / 256;
  const int PB = (MP * HC + 255) / 256;

  for (int t = 0; t < T_SEQ; ++t) {
    // ---- LSTM step t ----
    pack_xh<<<PK, 256, 0, stream>>>(dyn, h, packA, t);
    gemm_mfma<<<g_gates, 256, 0, stream>>>(packA, KP1, wcat_bf, KP1, bsum,
                                           agg, HC, MP, HC, KP1, 0);
    lstm_update<<<(N_NODES * HL + 255) / 256, 256, 0, stream>>>(agg, h, cst);

    // ---- GAT layer 1 ----
    pack_g1<<<PK, 256, 0, stream>>>(x_static, h, packA);
    gemm_mfma<<<g_xlr, 256, 0, stream>>>(packA, KP1, wlr1_bf, KP1, nullptr,
                                         xlr, 1024, MP, 2 * HC, KP1, 1);
    gat_edge<<<N_NODES, 256, 0, stream>>>(xlr, att1, bg1, rowstart, csr, agg);
    hipMemsetAsync(stats, 0, 2 * HC * sizeof(float), stream);
    bn_stats<<<160, 256, 0, stream>>>(agg, stats);
    bn_apply<<<PB, 256, 0, stream>>>(agg, stats, gamma1, beta1, aggb);

    // ---- GAT layer 2 ----
    gemm_mfma<<<g_xlr, 256, 0, stream>>>(aggb, HC, wlr2_bf, HC, nullptr,
                                         xlr, 1024, MP, 2 * HC, HC, 1);
    gat_edge<<<N_NODES, 256, 0, stream>>>(xlr, att2, bg2, rowstart, csr, agg);
    hipMemsetAsync(stats, 0, 2 * HC * sizeof(float), stream);
    bn_stats<<<160, 256, 0, stream>>>(agg, stats);
    bn_apply<<<PB, 256, 0, stream>>>(agg, stats, gamma2, beta2, aggb);

    // ---- output projection into out[n][t][:] ----
    gemm_mfma<<<g_proj, 256, 0, stream>>>(aggb, HC, wp_bf, HC, bp,
                                          out + t * EMB, T_SEQ * EMB,
                                          N_NODES, EMB, HC, 0);
  }
}

// Round 3
// 3241.752 us; speedup vs baseline: 2.3158x; 1.3191x over previous
//
#include <hip/hip_runtime.h>
#include <math.h>

typedef unsigned short u16;
typedef unsigned int u32;

#define N_NODES 20000
#define MP      20096            // N padded to multiple of 128
#define T_SEQ   8
#define DS      16
#define DD      8
#define E_EDGES 320000
#define HL      128
#define GH      4
#define GC      128
#define HC      512
#define EMB     64
#define KP1     160              // padded K for LSTM (136) and GAT1 (144)
#define EP      (E_EDGES + N_NODES)

typedef __attribute__((ext_vector_type(8))) short bf16x8;
typedef __attribute__((ext_vector_type(4))) float f32x4;

__device__ __forceinline__ u16 f2bf(float f) {
  u32 u = __float_as_uint(f);
  u += 0x7fff + ((u >> 16) & 1);   // RNE (inputs are finite)
  return (u16)(u >> 16);
}
__device__ __forceinline__ float bflo(u32 v) { return __uint_as_float(v << 16); }
__device__ __forceinline__ float bfhi(u32 v) { return __uint_as_float(v & 0xffff0000u); }

__device__ __forceinline__ void gld16(const void* g, void* l) {
  __builtin_amdgcn_global_load_lds(
      (const __attribute__((address_space(1))) void*)g,
      (__attribute__((address_space(3))) void*)l, 16, 0, 0);
}

// ---------------------------------------------------------------------------
// bf16 MFMA GEMM: C[M,Nc] = A[M,K] @ W[Nc,K]^T (+bias).
// 128x128 tile, BK=32, 4 waves -> 64x64 each (4x4 of 16x16x32 MFMA).
// global_load_lds width=16 staging; LDS layout row-major [128][32].
// ---------------------------------------------------------------------------
__global__ __launch_bounds__(256) void gemm_mfma(
    const u16* __restrict__ A, int lda,
    const u16* __restrict__ W, int ldw,
    const float* __restrict__ bias,
    void* __restrict__ Cout, int ldc,
    int M, int Nc, int K, int c_bf16)
{
  __shared__ u16 Asm[128 * 32];
  __shared__ u16 Bsm[128 * 32];
  const int tid = threadIdx.x;
  const int wave = tid >> 6, lane = tid & 63;
  const int wm = (wave >> 1) << 6, wn = (wave & 1) << 6;
  const int bm = blockIdx.y * 128, bn = blockIdx.x * 128;

  f32x4 acc[4][4];
#pragma unroll
  for (int i = 0; i < 4; ++i)
#pragma unroll
    for (int j = 0; j < 4; ++j) acc[i][j] = (f32x4){0.f, 0.f, 0.f, 0.f};

  const int qr = lane >> 2;          // row within 16-row chunk
  const int qc = (lane & 3) << 3;    // k-offset (0,8,16,24)
  const int q0 = wave * 2, q1 = wave * 2 + 1;
  const int ra0 = bm + q0 * 16 + qr;
  const int ra1 = bm + q1 * 16 + qr;
  int rb0 = bn + q0 * 16 + qr; if (rb0 >= Nc) rb0 = Nc - 1;
  int rb1 = bn + q1 * 16 + qr; if (rb1 >= Nc) rb1 = Nc - 1;

  const int fm = lane & 15;
  const int fk = (lane >> 4) << 3;

  for (int k0 = 0; k0 < K; k0 += 32) {
    gld16(A + (size_t)ra0 * lda + k0 + qc, &Asm[q0 * 512]);
    gld16(A + (size_t)ra1 * lda + k0 + qc, &Asm[q1 * 512]);
    gld16(W + (size_t)rb0 * ldw + k0 + qc, &Bsm[q0 * 512]);
    gld16(W + (size_t)rb1 * ldw + k0 + qc, &Bsm[q1 * 512]);
    __syncthreads();

    bf16x8 af[4], bfr[4];
#pragma unroll
    for (int i = 0; i < 4; ++i)
      af[i] = *(const bf16x8*)&Asm[(wm + i * 16 + fm) * 32 + fk];
#pragma unroll
    for (int j = 0; j < 4; ++j)
      bfr[j] = *(const bf16x8*)&Bsm[(wn + j * 16 + fm) * 32 + fk];
#pragma unroll
    for (int i = 0; i < 4; ++i)
#pragma unroll
      for (int j = 0; j < 4; ++j)
        acc[i][j] = __builtin_amdgcn_mfma_f32_16x16x32_bf16(af[i], bfr[j], acc[i][j], 0, 0, 0);
    __syncthreads();
  }

  const int cn = lane & 15, cm = (lane >> 4) << 2;
#pragma unroll
  for (int j = 0; j < 4; ++j) {
    const int c = bn + wn + j * 16 + cn;
    if (c >= Nc) continue;
    const float bb = bias ? bias[c] : 0.f;
#pragma unroll
    for (int i = 0; i < 4; ++i) {
#pragma unroll
      for (int r = 0; r < 4; ++r) {
        const int m = bm + wm + i * 16 + cm + r;
        if (m >= M) continue;
        const float v = acc[i][j][r] + bb;
        if (c_bf16) ((u16*)Cout)[(size_t)m * ldc + c] = f2bf(v);
        else        ((float*)Cout)[(size_t)m * ldc + c] = v;
      }
    }
  }
}

// ---------------------------------------------------------------------------
// Setup / conversion kernels (once per launch; tiny)
// ---------------------------------------------------------------------------
__global__ void k_bias_sum(const float* __restrict__ b_ih,
                           const float* __restrict__ b_hh,
                           float* __restrict__ bsum) {
  int i = blockIdx.x * blockDim.x + threadIdx.x;
  if (i < 4 * HL) bsum[i] = b_ih[i] + b_hh[i];
}

__global__ void k_wcat_bf(const float* __restrict__ W_ih,
                          const float* __restrict__ W_hh,
                          u16* __restrict__ w) {
  int idx = blockIdx.x * blockDim.x + threadIdx.x;
  if (idx >= HC * KP1) return;
  int j = idx / KP1, k = idx - j * KP1;
  float v = 0.f;
  if (k < DD) v = W_ih[j * DD + k];
  else if (k < DD + HL) v = W_hh[j * HL + (k - DD)];
  w[idx] = f2bf(v);
}

__global__ void k_wlr1_bf(const float* __restrict__ Wl,
                          const float* __restrict__ Wr,
                          u16* __restrict__ w) {
  int idx = blockIdx.x * blockDim.x + threadIdx.x;
  if (idx >= 2 * HC * KP1) return;
  int j = idx / KP1, k = idx - j * KP1;
  const float* src = (j < HC) ? Wl : Wr;
  int jj = j & (HC - 1);
  float v = (k < DS + HL) ? src[jj * (DS + HL) + k] : 0.f;
  w[idx] = f2bf(v);
}

__global__ void k_wlr2_bf(const float* __restrict__ Wl,
                          const float* __restrict__ Wr,
                          u16* __restrict__ w) {
  int idx = blockIdx.x * blockDim.x + threadIdx.x;
  if (idx >= 2 * HC * HC) return;
  int j = idx >> 9, k = idx & (HC - 1);
  const float* src = (j < HC) ? Wl : Wr;
  int jj = j & (HC - 1);
  w[idx] = f2bf(src[jj * HC + k]);
}

__global__ void k_wp_bf(const float* __restrict__ Wp, u16* __restrict__ w) {
  int idx = blockIdx.x * blockDim.x + threadIdx.x;
  if (idx < EMB * HC) w[idx] = f2bf(Wp[idx]);
}

// packG1 static cols (once per launch)
__global__ void k_pack_static(const float* __restrict__ xs, u16* __restrict__ packG1) {
  int idx = blockIdx.x * blockDim.x + threadIdx.x;
  if (idx >= N_NODES * DS) return;
  int n = idx >> 4, k = idx & 15;
  packG1[(size_t)n * KP1 + k] = f2bf(xs[idx]);
}

// packXH dyn cols (per step)
__global__ void k_pack_dyn(const float* __restrict__ dyn, u16* __restrict__ packXH, int t) {
  int idx = blockIdx.x * blockDim.x + threadIdx.x;
  if (idx >= N_NODES * DD) return;
  int n = idx >> 3, k = idx & 7;
  packXH[(size_t)n * KP1 + k] = f2bf(dyn[(size_t)n * (T_SEQ * DD) + t * DD + k]);
}

// LSTM pointwise; writes h (bf16) straight into both GEMM input buffers
__global__ void lstm_update(const float* __restrict__ gates,
                            float* __restrict__ c,
                            u16* __restrict__ packXH, u16* __restrict__ packG1) {
  int idx = blockIdx.x * blockDim.x + threadIdx.x;
  if (idx >= N_NODES * HL) return;
  int n = idx >> 7, j = idx & 127;
  const float* g = gates + (size_t)n * HC;
  float gi = g[j], gf = g[j + 128], gg = g[j + 256], go = g[j + 384];
  float si = 1.f / (1.f + __expf(-gi));
  float sf = 1.f / (1.f + __expf(-gf));
  float so = 1.f / (1.f + __expf(-go));
  float cn = sf * c[idx] + si * tanhf(gg);
  c[idx] = cn;
  u16 hb = f2bf(so * tanhf(cn));
  packXH[(size_t)n * KP1 + DD + j] = hb;
  packG1[(size_t)n * KP1 + DS + j] = hb;
}

// ---------------------------------------------------------------------------
// CSR build (dst-sorted), rebuilt every launch
// ---------------------------------------------------------------------------
__global__ void k_deg(const int* __restrict__ ei, int* __restrict__ deg) {
  int e = blockIdx.x * blockDim.x + threadIdx.x;
  if (e >= EP) return;
  int d = (e < E_EDGES) ? ei[E_EDGES + e] : (e - E_EDGES);
  atomicAdd(&deg[d], 1);
}

__global__ __launch_bounds__(1024) void k_scan(const int* __restrict__ deg,
                                               int* __restrict__ rowstart) {
  __shared__ int buf[1024];
  __shared__ int carry_s;
  const int tid = threadIdx.x;
  if (tid == 0) carry_s = 0;
  __syncthreads();
  for (int base = 0; base < N_NODES; base += 1024) {
    int v = (base + tid < N_NODES) ? deg[base + tid] : 0;
    buf[tid] = v;
    __syncthreads();
    for (int off = 1; off < 1024; off <<= 1) {
      int add = (tid >= off) ? buf[tid - off] : 0;
      __syncthreads();
      buf[tid] += add;
      __syncthreads();
    }
    int incl = buf[tid];
    int carry = carry_s;
    if (base + tid < N_NODES) rowstart[base + tid] = carry + incl - v;
    __syncthreads();
    if (tid == 1023) carry_s = carry + incl;
    __syncthreads();
  }
  if (tid == 0) rowstart[N_NODES] = carry_s;
}

__global__ void k_fill(const int* __restrict__ ei,
                       const int* __restrict__ rowstart,
                       int* __restrict__ cursor, int* __restrict__ csr) {
  int e = blockIdx.x * blockDim.x + threadIdx.x;
  if (e >= EP) return;
  int s, d;
  if (e < E_EDGES) { s = ei[e]; d = ei[E_EDGES + e]; }
  else             { s = d = e - E_EDGES; }
  int pos = atomicAdd(&cursor[d], 1);
  csr[rowstart[d] + pos] = s;
}

// ---------------------------------------------------------------------------
// GATv2 edge softmax + aggregation. xlr bf16 [MP,1024] (xl | xr).
// Block = 4 waves = 2 dst nodes; each wave covers 256 channels (2 heads),
// lane = 4 channels, reduce within 32-lane half-waves. Online softmax,
// single pass, 2-edge unrolled. Output bf16.
// ---------------------------------------------------------------------------
__global__ __launch_bounds__(256) void gat_edge(
    const u16* __restrict__ xlr,
    const float* __restrict__ att, const float* __restrict__ bias,
    const int* __restrict__ rowstart, const int* __restrict__ csr,
    u16* __restrict__ outb)
{
  const int wave = threadIdx.x >> 6, lane = threadIdx.x & 63;
  const int d = blockIdx.x * 2 + (wave >> 1);
  const int ch = ((wave & 1) << 8) + lane * 4;     // [0,512), lanes 0-31 head A, 32-63 head B
  const uint2 vr = *(const uint2*)(xlr + (size_t)d * 1024 + 512 + ch);
  const float rx0 = bflo(vr.x), rx1 = bfhi(vr.x), rx2 = bflo(vr.y), rx3 = bfhi(vr.y);
  const float4 av = *(const float4*)(att + ch);
  const int row = rowstart[d], end = rowstart[d + 1];
  const u32* __restrict__ base = (const u32*)xlr;  // u32 index = s*512 + ch/2
  const int cw = ch >> 1;

  float m = -INFINITY, l = 0.f, a0 = 0.f, a1 = 0.f, a2 = 0.f, a3 = 0.f;

#define GAT_STEP(v)                                                         \
  {                                                                         \
    const float x0 = bflo((v).x), x1 = bfhi((v).x);                         \
    const float x2 = bflo((v).y), x3 = bfhi((v).y);                         \
    const float e0 = x0 + rx0, e1 = x1 + rx1, e2 = x2 + rx2, e3 = x3 + rx3; \
    float pp = fmaxf(e0, 0.f) * av.x, pn = fminf(e0, 0.f) * av.x;           \
    pp = fmaf(fmaxf(e1, 0.f), av.y, pp); pn = fmaf(fminf(e1, 0.f), av.y, pn); \
    pp = fmaf(fmaxf(e2, 0.f), av.z, pp); pn = fmaf(fminf(e2, 0.f), av.z, pn); \
    pp = fmaf(fmaxf(e3, 0.f), av.w, pp); pn = fmaf(fminf(e3, 0.f), av.w, pn); \
    float p = fmaf(0.2f, pn, pp);                                           \
    _Pragma("unroll")                                                       \
    for (int off = 1; off < 32; off <<= 1) p += __shfl_xor(p, off);         \
    const float nm = fmaxf(m, p);                                           \
    const float sc = __expf(m - nm);                                        \
    const float w  = __expf(p - nm);                                        \
    l  = fmaf(l, sc, w);                                                    \
    a0 = fmaf(a0, sc, w * x0);                                              \
    a1 = fmaf(a1, sc, w * x1);                                              \
    a2 = fmaf(a2, sc, w * x2);                                              \
    a3 = fmaf(a3, sc, w * x3);                                              \
    m = nm;                                                                 \
  }

  int i = row;
  for (; i + 1 < end; i += 2) {
    const int s0 = csr[i], s1 = csr[i + 1];
    const uint2 v0 = *(const uint2*)(base + (size_t)s0 * 512 + cw);
    const uint2 v1 = *(const uint2*)(base + (size_t)s1 * 512 + cw);
    GAT_STEP(v0);
    GAT_STEP(v1);
  }
  if (i < end) {
    const int s0 = csr[i];
    const uint2 v0 = *(const uint2*)(base + (size_t)s0 * 512 + cw);
    GAT_STEP(v0);
  }
#undef GAT_STEP

  const float inv = 1.f / l;
  const float4 bv = *(const float4*)(bias + ch);
  const u32 o01 = (u32)f2bf(fmaf(a0, inv, bv.x)) | ((u32)f2bf(fmaf(a1, inv, bv.y)) << 16);
  const u32 o23 = (u32)f2bf(fmaf(a2, inv, bv.z)) | ((u32)f2bf(fmaf(a3, inv, bv.w)) << 16);
  *(uint2*)(outb + (size_t)d * HC + ch) = make_uint2(o01, o23);
}

// ---------------------------------------------------------------------------
// BatchNorm stats (bf16 input): stats[0..HC)=sum, [HC..2HC)=sumsq
// ---------------------------------------------------------------------------
__global__ __launch_bounds__(256) void bn_stats(const u16* __restrict__ x,
                                                float* __restrict__ stats) {
  const int tid = threadIdx.x;
  const int rows_per = (N_NODES + gridDim.x - 1) / gridDim.x;
  const int r0 = blockIdx.x * rows_per;
  const int r1 = min(r0 + rows_per, N_NODES);
  const u32* xp = (const u32*)x;
  float s0 = 0.f, s1 = 0.f, q0 = 0.f, q1 = 0.f;
  for (int r = r0; r < r1; ++r) {
    const u32 v = xp[(size_t)r * 256 + tid];
    const float v0 = bflo(v), v1 = bfhi(v);
    s0 += v0; q0 += v0 * v0;
    s1 += v1; q1 += v1 * v1;
  }
  atomicAdd(&stats[2 * tid],          s0);
  atomicAdd(&stats[2 * tid + 1],      s1);
  atomicAdd(&stats[HC + 2 * tid],     q0);
  atomicAdd(&stats[HC + 2 * tid + 1], q1);
}

__global__ void bn_apply(const u16* __restrict__ x, const float* __restrict__ stats,
                         const float* __restrict__ gamma, const float* __restrict__ beta,
                         u16* __restrict__ outb) {
  int idx = blockIdx.x * blockDim.x + threadIdx.x;
  if (idx >= N_NODES * (HC / 2)) return;
  const int cc = idx & (HC / 2 - 1);
  const int c0 = cc * 2, c1 = c0 + 1;
  const u32 v = ((const u32*)x)[idx];
  const float mean0 = stats[c0] * (1.f / N_NODES);
  const float mean1 = stats[c1] * (1.f / N_NODES);
  const float inv0 = rsqrtf(stats[HC + c0] * (1.f / N_NODES) - mean0 * mean0 + 1e-5f);
  const float inv1 = rsqrtf(stats[HC + c1] * (1.f / N_NODES) - mean1 * mean1 + 1e-5f);
  float z0 = (bflo(v) - mean0) * inv0 * gamma[c0] + beta[c0];
  float z1 = (bfhi(v) - mean1) * inv1 * gamma[c1] + beta[c1];
  z0 = z0 > 0.f ? z0 : 0.f;
  z1 = z1 > 0.f ? z1 : 0.f;
  ((u32*)outb)[idx] = (u32)f2bf(z0) | ((u32)f2bf(z1) << 16);
}

// ---------------------------------------------------------------------------
extern "C" void kernel_launch(void* const* d_in, const int* in_sizes, int n_in,
                              void* d_out, int out_size, void* d_ws, size_t ws_size,
                              hipStream_t stream) {
  const float* x_static = (const float*)d_in[0];
  const float* dyn      = (const float*)d_in[1];
  const int*   ei       = (const int*)d_in[2];
  const float* W_ih     = (const float*)d_in[3];
  const float* W_hh     = (const float*)d_in[4];
  const float* b_ih     = (const float*)d_in[5];
  const float* b_hh     = (const float*)d_in[6];
  const float* Wl1      = (const float*)d_in[7];
  const float* Wr1      = (const float*)d_in[8];
  const float* att1     = (const float*)d_in[9];
  const float* bg1      = (const float*)d_in[10];
  const float* Wl2      = (const float*)d_in[11];
  const float* Wr2      = (const float*)d_in[12];
  const float* att2     = (const float*)d_in[13];
  const float* bg2      = (const float*)d_in[14];
  const float* gamma1   = (const float*)d_in[15];
  const float* beta1    = (const float*)d_in[16];
  const float* gamma2   = (const float*)d_in[17];
  const float* beta2    = (const float*)d_in[18];
  const float* Wp       = (const float*)d_in[19];
  const float* bp       = (const float*)d_in[20];
  float* out = (float*)d_out;

  // ---- workspace carve (float units) ----
  float* ws = (float*)d_ws;
  size_t o = 0;
  float* c     = ws + o; o += (size_t)MP * HL;
  float* gates = ws + o; o += (size_t)MP * HC;
  float* stats = ws + o; o += 4 * HC;
  float* bsum  = ws + o; o += 4 * HL;
  u16* packXH  = (u16*)(ws + o); o += (size_t)MP * KP1 / 2;
  u16* packG1  = (u16*)(ws + o); o += (size_t)MP * KP1 / 2;
  u16* xlr     = (u16*)(ws + o); o += (size_t)MP * 1024 / 2;
  u16* gout    = (u16*)(ws + o); o += (size_t)MP * HC / 2;
  u16* aggb    = (u16*)(ws + o); o += (size_t)MP * HC / 2;
  u16* wcat_bf = (u16*)(ws + o); o += (size_t)HC * KP1 / 2;
  u16* wlr1_bf = (u16*)(ws + o); o += (size_t)2 * HC * KP1 / 2;
  u16* wlr2_bf = (u16*)(ws + o); o += (size_t)2 * HC * HC / 2;
  u16* wp_bf   = (u16*)(ws + o); o += (size_t)EMB * HC / 2;
  int* deg      = (int*)(ws + o); o += N_NODES;
  int* cursor   = (int*)(ws + o); o += N_NODES;
  int* rowstart = (int*)(ws + o); o += N_NODES + 64;
  int* csr      = (int*)(ws + o); o += EP;

  // ---- per-launch init ----
  hipMemsetAsync(deg,    0, N_NODES * sizeof(int), stream);
  hipMemsetAsync(cursor, 0, N_NODES * sizeof(int), stream);
  hipMemsetAsync(c,      0, (size_t)MP * HL * sizeof(float), stream);
  hipMemsetAsync(packXH, 0, (size_t)MP * KP1 * sizeof(u16), stream);  // h=0 + pads
  hipMemsetAsync(packG1, 0, (size_t)MP * KP1 * sizeof(u16), stream);
  hipMemsetAsync(aggb,   0, (size_t)MP * HC * sizeof(u16), stream);   // pad rows

  k_bias_sum<<<2, 256, 0, stream>>>(b_ih, b_hh, bsum);
  k_wcat_bf<<<(HC * KP1 + 255) / 256, 256, 0, stream>>>(W_ih, W_hh, wcat_bf);
  k_wlr1_bf<<<(2 * HC * KP1 + 255) / 256, 256, 0, stream>>>(Wl1, Wr1, wlr1_bf);
  k_wlr2_bf<<<(2 * HC * HC + 255) / 256, 256, 0, stream>>>(Wl2, Wr2, wlr2_bf);
  k_wp_bf<<<(EMB * HC + 255) / 256, 256, 0, stream>>>(Wp, wp_bf);
  k_pack_static<<<(N_NODES * DS + 255) / 256, 256, 0, stream>>>(x_static, packG1);
  k_deg<<<(EP + 255) / 256, 256, 0, stream>>>(ei, deg);
  k_scan<<<1, 1024, 0, stream>>>(deg, rowstart);
  k_fill<<<(EP + 255) / 256, 256, 0, stream>>>(ei, rowstart, cursor, csr);

  const int GY = MP / 128;                       // 157
  const dim3 g_gates(HC / 128, GY);              // (4,157)
  const dim3 g_xlr(2 * HC / 128, GY);            // (8,157)
  const dim3 g_proj(1, GY);                      // (1,157)

  for (int t = 0; t < T_SEQ; ++t) {
    // ---- LSTM step t ----
    k_pack_dyn<<<(N_NODES * DD + 255) / 256, 256, 0, stream>>>(dyn, packXH, t);
    gemm_mfma<<<g_gates, 256, 0, stream>>>(packXH, KP1, wcat_bf, KP1, bsum,
                                           gates, HC, MP, HC, KP1, 0);
    lstm_update<<<(N_NODES * HL + 255) / 256, 256, 0, stream>>>(gates, c, packXH, packG1);

    hipMemsetAsync(stats, 0, 4 * HC * sizeof(float), stream);

    // ---- GAT layer 1 ----
    gemm_mfma<<<g_xlr, 256, 0, stream>>>(packG1, KP1, wlr1_bf, KP1, nullptr,
                                         xlr, 1024, MP, 2 * HC, KP1, 1);
    gat_edge<<<N_NODES / 2, 256, 0, stream>>>(xlr, att1, bg1, rowstart, csr, gout);
    bn_stats<<<160, 256, 0, stream>>>(gout, stats);
    bn_apply<<<(N_NODES * HC / 2 + 255) / 256, 256, 0, stream>>>(gout, stats,
                                                                 gamma1, beta1, aggb);

    // ---- GAT layer 2 ----
    gemm_mfma<<<g_xlr, 256, 0, stream>>>(aggb, HC, wlr2_bf, HC, nullptr,
                                         xlr, 1024, MP, 2 * HC, HC, 1);
    gat_edge<<<N_NODES / 2, 256, 0, stream>>>(xlr, att2, bg2, rowstart, csr, gout);
    bn_stats<<<160, 256, 0, stream>>>(gout, stats + 2 * HC);
    bn_apply<<<(N_NODES * HC / 2 + 255) / 256, 256, 0, stream>>>(gout, stats + 2 * HC,
                                                                 gamma2, beta2, aggb);

    // ---- output projection into out[n][t][:] ----
    gemm_mfma<<<g_proj, 256, 0, stream>>>(aggb, HC, wp_bf, HC, bp,
                                          out + t * EMB, T_SEQ * EMB,
                                          N_NODES, EMB, HC, 0);
  }
}

// Round 4
// 3075.439 us; speedup vs baseline: 2.4410x; 1.0541x over previous
//
#include <hip/hip_runtime.h>
#include <math.h>

typedef unsigned short u16;
typedef unsigned int u32;

#define N_NODES 20000
#define MP      20096            // N padded to multiple of 128
#define T_SEQ   8
#define DS      16
#define DD      8
#define E_EDGES 320000
#define HL      128
#define GH      4
#define GC      128
#define HC      512
#define EMB     64
#define KP1     160              // padded K for LSTM (136) and GAT1 (144)
#define EP      (E_EDGES + N_NODES)

typedef __attribute__((ext_vector_type(8))) short bf16x8;
typedef __attribute__((ext_vector_type(4))) float f32x4;

__device__ __forceinline__ u16 f2bf(float f) {
  u32 u = __float_as_uint(f);
  u += 0x7fff + ((u >> 16) & 1);   // RNE (inputs are finite)
  return (u16)(u >> 16);
}
__device__ __forceinline__ float bflo(u32 v) { return __uint_as_float(v << 16); }
__device__ __forceinline__ float bfhi(u32 v) { return __uint_as_float(v & 0xffff0000u); }

__device__ __forceinline__ float4 f4add(float4 a, float4 b) {
  return make_float4(a.x + b.x, a.y + b.y, a.z + b.z, a.w + b.w);
}
__device__ __forceinline__ float4 f4fma(float4 a, float4 b, float4 c) {
  return make_float4(fmaf(a.x, b.x, c.x), fmaf(a.y, b.y, c.y),
                     fmaf(a.z, b.z, c.z), fmaf(a.w, b.w, c.w));
}
__device__ __forceinline__ float4 f4fmas(float s, float4 b, float4 c) {
  return make_float4(fmaf(s, b.x, c.x), fmaf(s, b.y, c.y),
                     fmaf(s, b.z, c.z), fmaf(s, b.w, c.w));
}
__device__ __forceinline__ float4 f4max0(float4 a) {
  return make_float4(fmaxf(a.x, 0.f), fmaxf(a.y, 0.f), fmaxf(a.z, 0.f), fmaxf(a.w, 0.f));
}
__device__ __forceinline__ float4 f4min0(float4 a) {
  return make_float4(fminf(a.x, 0.f), fminf(a.y, 0.f), fminf(a.z, 0.f), fminf(a.w, 0.f));
}

__device__ __forceinline__ void gld16(const void* g, void* l) {
  __builtin_amdgcn_global_load_lds(
      (const __attribute__((address_space(1))) void*)g,
      (__attribute__((address_space(3))) void*)l, 16, 0, 0);
}

// ---------------------------------------------------------------------------
// bf16 MFMA GEMM: C[M,Nc] = A[M,K] @ W[Nc,K]^T (+bias).
// 128x128 tile, BK=32, 4 waves -> 64x64 each (4x4 of 16x16x32 MFMA).
// global_load_lds width=16 staging; LDS layout row-major [128][32].
// ---------------------------------------------------------------------------
__global__ __launch_bounds__(256) void gemm_mfma(
    const u16* __restrict__ A, int lda,
    const u16* __restrict__ W, int ldw,
    const float* __restrict__ bias,
    void* __restrict__ Cout, int ldc,
    int M, int Nc, int K, int c_bf16)
{
  __shared__ u16 Asm[128 * 32];
  __shared__ u16 Bsm[128 * 32];
  const int tid = threadIdx.x;
  const int wave = tid >> 6, lane = tid & 63;
  const int wm = (wave >> 1) << 6, wn = (wave & 1) << 6;
  const int bm = blockIdx.y * 128, bn = blockIdx.x * 128;

  f32x4 acc[4][4];
#pragma unroll
  for (int i = 0; i < 4; ++i)
#pragma unroll
    for (int j = 0; j < 4; ++j) acc[i][j] = (f32x4){0.f, 0.f, 0.f, 0.f};

  const int qr = lane >> 2;          // row within 16-row chunk
  const int qc = (lane & 3) << 3;    // k-offset (0,8,16,24)
  const int q0 = wave * 2, q1 = wave * 2 + 1;
  const int ra0 = bm + q0 * 16 + qr;
  const int ra1 = bm + q1 * 16 + qr;
  int rb0 = bn + q0 * 16 + qr; if (rb0 >= Nc) rb0 = Nc - 1;
  int rb1 = bn + q1 * 16 + qr; if (rb1 >= Nc) rb1 = Nc - 1;

  const int fm = lane & 15;
  const int fk = (lane >> 4) << 3;

  for (int k0 = 0; k0 < K; k0 += 32) {
    gld16(A + (size_t)ra0 * lda + k0 + qc, &Asm[q0 * 512]);
    gld16(A + (size_t)ra1 * lda + k0 + qc, &Asm[q1 * 512]);
    gld16(W + (size_t)rb0 * ldw + k0 + qc, &Bsm[q0 * 512]);
    gld16(W + (size_t)rb1 * ldw + k0 + qc, &Bsm[q1 * 512]);
    __syncthreads();

    bf16x8 af[4], bfr[4];
#pragma unroll
    for (int i = 0; i < 4; ++i)
      af[i] = *(const bf16x8*)&Asm[(wm + i * 16 + fm) * 32 + fk];
#pragma unroll
    for (int j = 0; j < 4; ++j)
      bfr[j] = *(const bf16x8*)&Bsm[(wn + j * 16 + fm) * 32 + fk];
#pragma unroll
    for (int i = 0; i < 4; ++i)
#pragma unroll
      for (int j = 0; j < 4; ++j)
        acc[i][j] = __builtin_amdgcn_mfma_f32_16x16x32_bf16(af[i], bfr[j], acc[i][j], 0, 0, 0);
    __syncthreads();
  }

  const int cn = lane & 15, cm = (lane >> 4) << 2;
#pragma unroll
  for (int j = 0; j < 4; ++j) {
    const int c = bn + wn + j * 16 + cn;
    if (c >= Nc) continue;
    const float bb = bias ? bias[c] : 0.f;
#pragma unroll
    for (int i = 0; i < 4; ++i) {
#pragma unroll
      for (int r = 0; r < 4; ++r) {
        const int m = bm + wm + i * 16 + cm + r;
        if (m >= M) continue;
        const float v = acc[i][j][r] + bb;
        if (c_bf16) ((u16*)Cout)[(size_t)m * ldc + c] = f2bf(v);
        else        ((float*)Cout)[(size_t)m * ldc + c] = v;
      }
    }
  }
}

// ---------------------------------------------------------------------------
// Setup / conversion kernels (once per launch; tiny)
// ---------------------------------------------------------------------------
__global__ void k_bias_sum(const float* __restrict__ b_ih,
                           const float* __restrict__ b_hh,
                           float* __restrict__ bsum) {
  int i = blockIdx.x * blockDim.x + threadIdx.x;
  if (i < 4 * HL) bsum[i] = b_ih[i] + b_hh[i];
}

__global__ void k_wcat_bf(const float* __restrict__ W_ih,
                          const float* __restrict__ W_hh,
                          u16* __restrict__ w) {
  int idx = blockIdx.x * blockDim.x + threadIdx.x;
  if (idx >= HC * KP1) return;
  int j = idx / KP1, k = idx - j * KP1;
  float v = 0.f;
  if (k < DD) v = W_ih[j * DD + k];
  else if (k < DD + HL) v = W_hh[j * HL + (k - DD)];
  w[idx] = f2bf(v);
}

__global__ void k_wlr1_bf(const float* __restrict__ Wl,
                          const float* __restrict__ Wr,
                          u16* __restrict__ w) {
  int idx = blockIdx.x * blockDim.x + threadIdx.x;
  if (idx >= 2 * HC * KP1) return;
  int j = idx / KP1, k = idx - j * KP1;
  const float* src = (j < HC) ? Wl : Wr;
  int jj = j & (HC - 1);
  float v = (k < DS + HL) ? src[jj * (DS + HL) + k] : 0.f;
  w[idx] = f2bf(v);
}

__global__ void k_wlr2_bf(const float* __restrict__ Wl,
                          const float* __restrict__ Wr,
                          u16* __restrict__ w) {
  int idx = blockIdx.x * blockDim.x + threadIdx.x;
  if (idx >= 2 * HC * HC) return;
  int j = idx >> 9, k = idx & (HC - 1);
  const float* src = (j < HC) ? Wl : Wr;
  int jj = j & (HC - 1);
  w[idx] = f2bf(src[jj * HC + k]);
}

__global__ void k_wp_bf(const float* __restrict__ Wp, u16* __restrict__ w) {
  int idx = blockIdx.x * blockDim.x + threadIdx.x;
  if (idx < EMB * HC) w[idx] = f2bf(Wp[idx]);
}

// packG1 static cols (once per launch)
__global__ void k_pack_static(const float* __restrict__ xs, u16* __restrict__ packG1) {
  int idx = blockIdx.x * blockDim.x + threadIdx.x;
  if (idx >= N_NODES * DS) return;
  int n = idx >> 4, k = idx & 15;
  packG1[(size_t)n * KP1 + k] = f2bf(xs[idx]);
}

// packXH dyn cols for t=0 only (later steps written by lstm_update)
__global__ void k_pack_dyn(const float* __restrict__ dyn, u16* __restrict__ packXH) {
  int idx = blockIdx.x * blockDim.x + threadIdx.x;
  if (idx >= N_NODES * DD) return;
  int n = idx >> 3, k = idx & 7;
  packXH[(size_t)n * KP1 + k] = f2bf(dyn[(size_t)n * (T_SEQ * DD) + k]);
}

// LSTM pointwise; writes h (bf16) into both GEMM inputs and next step's dyn cols
__global__ void lstm_update(const float* __restrict__ gates,
                            float* __restrict__ c,
                            u16* __restrict__ packXH, u16* __restrict__ packG1,
                            const float* __restrict__ dyn, int t_next) {
  int idx = blockIdx.x * blockDim.x + threadIdx.x;
  if (idx >= N_NODES * HL) return;
  int n = idx >> 7, j = idx & 127;
  const float* g = gates + (size_t)n * HC;
  float gi = g[j], gf = g[j + 128], gg = g[j + 256], go = g[j + 384];
  float si = 1.f / (1.f + __expf(-gi));
  float sf = 1.f / (1.f + __expf(-gf));
  float so = 1.f / (1.f + __expf(-go));
  float cn = sf * c[idx] + si * tanhf(gg);
  c[idx] = cn;
  u16 hb = f2bf(so * tanhf(cn));
  packXH[(size_t)n * KP1 + DD + j] = hb;
  packG1[(size_t)n * KP1 + DS + j] = hb;
  if (j < DD && t_next < T_SEQ)
    packXH[(size_t)n * KP1 + j] =
        f2bf(dyn[(size_t)n * (T_SEQ * DD) + t_next * DD + j]);
}

// ---------------------------------------------------------------------------
// CSR build (dst-sorted), rebuilt every launch
// ---------------------------------------------------------------------------
__global__ void k_deg(const int* __restrict__ ei, int* __restrict__ deg) {
  int e = blockIdx.x * blockDim.x + threadIdx.x;
  if (e >= EP) return;
  int d = (e < E_EDGES) ? ei[E_EDGES + e] : (e - E_EDGES);
  atomicAdd(&deg[d], 1);
}

__global__ __launch_bounds__(1024) void k_scan(const int* __restrict__ deg,
                                               int* __restrict__ rowstart) {
  __shared__ int buf[1024];
  __shared__ int carry_s;
  const int tid = threadIdx.x;
  if (tid == 0) carry_s = 0;
  __syncthreads();
  for (int base = 0; base < N_NODES; base += 1024) {
    int v = (base + tid < N_NODES) ? deg[base + tid] : 0;
    buf[tid] = v;
    __syncthreads();
    for (int off = 1; off < 1024; off <<= 1) {
      int add = (tid >= off) ? buf[tid - off] : 0;
      __syncthreads();
      buf[tid] += add;
      __syncthreads();
    }
    int incl = buf[tid];
    int carry = carry_s;
    if (base + tid < N_NODES) rowstart[base + tid] = carry + incl - v;
    __syncthreads();
    if (tid == 1023) carry_s = carry + incl;
    __syncthreads();
  }
  if (tid == 0) rowstart[N_NODES] = carry_s;
}

__global__ void k_fill(const int* __restrict__ ei,
                       const int* __restrict__ rowstart,
                       int* __restrict__ cursor, int* __restrict__ csr) {
  int e = blockIdx.x * blockDim.x + threadIdx.x;
  if (e >= EP) return;
  int s, d;
  if (e < E_EDGES) { s = ei[e]; d = ei[E_EDGES + e]; }
  else             { s = d = e - E_EDGES; }
  int pos = atomicAdd(&cursor[d], 1);
  csr[rowstart[d] + pos] = s;
}

// ---------------------------------------------------------------------------
// GATv2 edge softmax + aggregation v3. xlr bf16 [MP,1024] (xl | xr).
// One wave per dst; lane = 8 channels (uint4 gather); heads = 16-lane groups.
// No max subtraction (scores provably small; softmax shift-invariant).
// Block = 4 waves = 4 dst. Output bf16.
// ---------------------------------------------------------------------------
__global__ __launch_bounds__(256) void gat_edge(
    const u16* __restrict__ xlr,
    const float* __restrict__ att, const float* __restrict__ bias,
    const int* __restrict__ rowstart, const int* __restrict__ csr,
    u16* __restrict__ outb)
{
  const int wave = threadIdx.x >> 6, lane = threadIdx.x & 63;
  const int d = blockIdx.x * 4 + wave;
  const int ch = lane * 8;                  // [0,512); head = lane>>4
  const uint4 vr = *(const uint4*)(xlr + (size_t)d * 1024 + 512 + ch);
  const float4 rxa = make_float4(bflo(vr.x), bfhi(vr.x), bflo(vr.y), bfhi(vr.y));
  const float4 rxb = make_float4(bflo(vr.z), bfhi(vr.z), bflo(vr.w), bfhi(vr.w));
  const float4 ava = *(const float4*)(att + ch);
  const float4 avb = *(const float4*)(att + ch + 4);
  const int row = rowstart[d], end = rowstart[d + 1];
  const u16* __restrict__ xbase = xlr + ch;   // + s*1024 per edge

  float l = 0.f;
  float4 aca = make_float4(0.f, 0.f, 0.f, 0.f);
  float4 acb = make_float4(0.f, 0.f, 0.f, 0.f);

#define GAT_STEP(v)                                                          \
  {                                                                          \
    const float4 xa = make_float4(bflo((v).x), bfhi((v).x), bflo((v).y), bfhi((v).y)); \
    const float4 xb = make_float4(bflo((v).z), bfhi((v).z), bflo((v).w), bfhi((v).w)); \
    const float4 ea = f4add(xa, rxa), eb = f4add(xb, rxb);                   \
    float4 pp = f4fma(f4max0(ea), ava, make_float4(0.f, 0.f, 0.f, 0.f));     \
    pp = f4fma(f4max0(eb), avb, pp);                                         \
    float4 pn = f4fma(f4min0(ea), ava, make_float4(0.f, 0.f, 0.f, 0.f));     \
    pn = f4fma(f4min0(eb), avb, pn);                                         \
    const float4 pt = f4fmas(0.2f, pn, pp);                                  \
    float p = (pt.x + pt.y) + (pt.z + pt.w);                                 \
    _Pragma("unroll")                                                        \
    for (int off = 1; off < 16; off <<= 1) p += __shfl_xor(p, off);          \
    const float w = __expf(p);                                               \
    l += w;                                                                  \
    aca = f4fmas(w, xa, aca);                                                \
    acb = f4fmas(w, xb, acb);                                                \
  }

  int i = row;
  for (; i + 1 < end; i += 2) {
    const int s0 = csr[i], s1 = csr[i + 1];
    const uint4 v0 = *(const uint4*)(xbase + ((size_t)s0 << 10));
    const uint4 v1 = *(const uint4*)(xbase + ((size_t)s1 << 10));
    GAT_STEP(v0);
    GAT_STEP(v1);
  }
  if (i < end) {
    const int s0 = csr[i];
    const uint4 v0 = *(const uint4*)(xbase + ((size_t)s0 << 10));
    GAT_STEP(v0);
  }
#undef GAT_STEP

  const float inv = 1.f / l;
  const float4 ba = *(const float4*)(bias + ch);
  const float4 bb = *(const float4*)(bias + ch + 4);
  uint4 ov;
  ov.x = (u32)f2bf(fmaf(aca.x, inv, ba.x)) | ((u32)f2bf(fmaf(aca.y, inv, ba.y)) << 16);
  ov.y = (u32)f2bf(fmaf(aca.z, inv, ba.z)) | ((u32)f2bf(fmaf(aca.w, inv, ba.w)) << 16);
  ov.z = (u32)f2bf(fmaf(acb.x, inv, bb.x)) | ((u32)f2bf(fmaf(acb.y, inv, bb.y)) << 16);
  ov.w = (u32)f2bf(fmaf(acb.z, inv, bb.z)) | ((u32)f2bf(fmaf(acb.w, inv, bb.w)) << 16);
  *(uint4*)(outb + (size_t)d * HC + ch) = ov;
}

// ---------------------------------------------------------------------------
// BatchNorm stats (bf16 input): stats[0..HC)=sum, [HC..2HC)=sumsq
// ---------------------------------------------------------------------------
__global__ __launch_bounds__(256) void bn_stats(const u16* __restrict__ x,
                                                float* __restrict__ stats) {
  const int tid = threadIdx.x;
  const int rows_per = (N_NODES + gridDim.x - 1) / gridDim.x;
  const int r0 = blockIdx.x * rows_per;
  const int r1 = min(r0 + rows_per, N_NODES);
  const u32* xp = (const u32*)x;
  float s0 = 0.f, s1 = 0.f, q0 = 0.f, q1 = 0.f;
  for (int r = r0; r < r1; ++r) {
    const u32 v = xp[(size_t)r * 256 + tid];
    const float v0 = bflo(v), v1 = bfhi(v);
    s0 += v0; q0 += v0 * v0;
    s1 += v1; q1 += v1 * v1;
  }
  atomicAdd(&stats[2 * tid],          s0);
  atomicAdd(&stats[2 * tid + 1],      s1);
  atomicAdd(&stats[HC + 2 * tid],     q0);
  atomicAdd(&stats[HC + 2 * tid + 1], q1);
}

__global__ void bn_apply(const u16* __restrict__ x, const float* __restrict__ stats,
                         const float* __restrict__ gamma, const float* __restrict__ beta,
                         u16* __restrict__ outb) {
  int idx = blockIdx.x * blockDim.x + threadIdx.x;
  if (idx >= N_NODES * (HC / 2)) return;
  const int cc = idx & (HC / 2 - 1);
  const int c0 = cc * 2, c1 = c0 + 1;
  const u32 v = ((const u32*)x)[idx];
  const float mean0 = stats[c0] * (1.f / N_NODES);
  const float mean1 = stats[c1] * (1.f / N_NODES);
  const float inv0 = rsqrtf(stats[HC + c0] * (1.f / N_NODES) - mean0 * mean0 + 1e-5f);
  const float inv1 = rsqrtf(stats[HC + c1] * (1.f / N_NODES) - mean1 * mean1 + 1e-5f);
  float z0 = (bflo(v) - mean0) * inv0 * gamma[c0] + beta[c0];
  float z1 = (bfhi(v) - mean1) * inv1 * gamma[c1] + beta[c1];
  z0 = z0 > 0.f ? z0 : 0.f;
  z1 = z1 > 0.f ? z1 : 0.f;
  ((u32*)outb)[idx] = (u32)f2bf(z0) | ((u32)f2bf(z1) << 16);
}

// ---------------------------------------------------------------------------
extern "C" void kernel_launch(void* const* d_in, const int* in_sizes, int n_in,
                              void* d_out, int out_size, void* d_ws, size_t ws_size,
                              hipStream_t stream) {
  const float* x_static = (const float*)d_in[0];
  const float* dyn      = (const float*)d_in[1];
  const int*   ei       = (const int*)d_in[2];
  const float* W_ih     = (const float*)d_in[3];
  const float* W_hh     = (const float*)d_in[4];
  const float* b_ih     = (const float*)d_in[5];
  const float* b_hh     = (const float*)d_in[6];
  const float* Wl1      = (const float*)d_in[7];
  const float* Wr1      = (const float*)d_in[8];
  const float* att1     = (const float*)d_in[9];
  const float* bg1      = (const float*)d_in[10];
  const float* Wl2      = (const float*)d_in[11];
  const float* Wr2      = (const float*)d_in[12];
  const float* att2     = (const float*)d_in[13];
  const float* bg2      = (const float*)d_in[14];
  const float* gamma1   = (const float*)d_in[15];
  const float* beta1    = (const float*)d_in[16];
  const float* gamma2   = (const float*)d_in[17];
  const float* beta2    = (const float*)d_in[18];
  const float* Wp       = (const float*)d_in[19];
  const float* bp       = (const float*)d_in[20];
  float* out = (float*)d_out;

  // ---- workspace carve (float units) ----
  float* ws = (float*)d_ws;
  size_t o = 0;
  float* c     = ws + o; o += (size_t)MP * HL;
  float* gates = ws + o; o += (size_t)MP * HC;
  float* stats = ws + o; o += 4 * HC;
  float* bsum  = ws + o; o += 4 * HL;
  u16* packXH  = (u16*)(ws + o); o += (size_t)MP * KP1 / 2;
  u16* packG1  = (u16*)(ws + o); o += (size_t)MP * KP1 / 2;
  u16* xlr     = (u16*)(ws + o); o += (size_t)MP * 1024 / 2;
  u16* gout    = (u16*)(ws + o); o += (size_t)MP * HC / 2;
  u16* aggb    = (u16*)(ws + o); o += (size_t)MP * HC / 2;
  u16* wcat_bf = (u16*)(ws + o); o += (size_t)HC * KP1 / 2;
  u16* wlr1_bf = (u16*)(ws + o); o += (size_t)2 * HC * KP1 / 2;
  u16* wlr2_bf = (u16*)(ws + o); o += (size_t)2 * HC * HC / 2;
  u16* wp_bf   = (u16*)(ws + o); o += (size_t)EMB * HC / 2;
  int* deg      = (int*)(ws + o); o += N_NODES;
  int* cursor   = (int*)(ws + o); o += N_NODES;
  int* rowstart = (int*)(ws + o); o += N_NODES + 64;
  int* csr      = (int*)(ws + o); o += EP;

  // ---- per-launch init ----
  hipMemsetAsync(deg,    0, N_NODES * sizeof(int), stream);
  hipMemsetAsync(cursor, 0, N_NODES * sizeof(int), stream);
  hipMemsetAsync(c,      0, (size_t)MP * HL * sizeof(float), stream);
  hipMemsetAsync(packXH, 0, (size_t)MP * KP1 * sizeof(u16), stream);  // h=0 + pads
  hipMemsetAsync(packG1, 0, (size_t)MP * KP1 * sizeof(u16), stream);
  hipMemsetAsync(aggb,   0, (size_t)MP * HC * sizeof(u16), stream);   // pad rows

  k_bias_sum<<<2, 256, 0, stream>>>(b_ih, b_hh, bsum);
  k_wcat_bf<<<(HC * KP1 + 255) / 256, 256, 0, stream>>>(W_ih, W_hh, wcat_bf);
  k_wlr1_bf<<<(2 * HC * KP1 + 255) / 256, 256, 0, stream>>>(Wl1, Wr1, wlr1_bf);
  k_wlr2_bf<<<(2 * HC * HC + 255) / 256, 256, 0, stream>>>(Wl2, Wr2, wlr2_bf);
  k_wp_bf<<<(EMB * HC + 255) / 256, 256, 0, stream>>>(Wp, wp_bf);
  k_pack_static<<<(N_NODES * DS + 255) / 256, 256, 0, stream>>>(x_static, packG1);
  k_pack_dyn<<<(N_NODES * DD + 255) / 256, 256, 0, stream>>>(dyn, packXH);
  k_deg<<<(EP + 255) / 256, 256, 0, stream>>>(ei, deg);
  k_scan<<<1, 1024, 0, stream>>>(deg, rowstart);
  k_fill<<<(EP + 255) / 256, 256, 0, stream>>>(ei, rowstart, cursor, csr);

  const int GY = MP / 128;                       // 157
  const dim3 g_gates(HC / 128, GY);              // (4,157)
  const dim3 g_xlr(2 * HC / 128, GY);            // (8,157)
  const dim3 g_proj(1, GY);                      // (1,157)

  for (int t = 0; t < T_SEQ; ++t) {
    // ---- LSTM step t ----
    gemm_mfma<<<g_gates, 256, 0, stream>>>(packXH, KP1, wcat_bf, KP1, bsum,
                                           gates, HC, MP, HC, KP1, 0);
    lstm_update<<<(N_NODES * HL + 255) / 256, 256, 0, stream>>>(
        gates, c, packXH, packG1, dyn, t + 1);

    hipMemsetAsync(stats, 0, 4 * HC * sizeof(float), stream);

    // ---- GAT layer 1 ----
    gemm_mfma<<<g_xlr, 256, 0, stream>>>(packG1, KP1, wlr1_bf, KP1, nullptr,
                                         xlr, 1024, MP, 2 * HC, KP1, 1);
    gat_edge<<<N_NODES / 4, 256, 0, stream>>>(xlr, att1, bg1, rowstart, csr, gout);
    bn_stats<<<500, 256, 0, stream>>>(gout, stats);
    bn_apply<<<(N_NODES * HC / 2 + 255) / 256, 256, 0, stream>>>(gout, stats,
                                                                 gamma1, beta1, aggb);

    // ---- GAT layer 2 ----
    gemm_mfma<<<g_xlr, 256, 0, stream>>>(aggb, HC, wlr2_bf, HC, nullptr,
                                         xlr, 1024, MP, 2 * HC, HC, 1);
    gat_edge<<<N_NODES / 4, 256, 0, stream>>>(xlr, att2, bg2, rowstart, csr, gout);
    bn_stats<<<500, 256, 0, stream>>>(gout, stats + 2 * HC);
    bn_apply<<<(N_NODES * HC / 2 + 255) / 256, 256, 0, stream>>>(gout, stats + 2 * HC,
                                                                 gamma2, beta2, aggb);

    // ---- output projection into out[n][t][:] ----
    gemm_mfma<<<g_proj, 256, 0, stream>>>(aggb, HC, wp_bf, HC, bp,
                                          out + t * EMB, T_SEQ * EMB,
                                          N_NODES, EMB, HC, 0);
  }
}

// Round 5
// 2896.071 us; speedup vs baseline: 2.5922x; 1.0619x over previous
//
#include <hip/hip_runtime.h>
#include <math.h>

typedef unsigned short u16;
typedef unsigned int u32;

#define N_NODES 20000
#define MP      20096            // N padded to multiple of 128
#define T_SEQ   8
#define DS      16
#define DD      8
#define E_EDGES 320000
#define HL      128
#define GH      4
#define GC      128
#define HC      512
#define EMB     64
#define KP1     160              // padded K for LSTM (136) and GAT1 (144)
#define EP      (E_EDGES + N_NODES)

typedef __attribute__((ext_vector_type(8))) short bf16x8;
typedef __attribute__((ext_vector_type(4))) float f32x4;

__device__ __forceinline__ u16 f2bf(float f) {
  u32 u = __float_as_uint(f);
  u += 0x7fff + ((u >> 16) & 1);   // RNE (inputs are finite)
  return (u16)(u >> 16);
}
__device__ __forceinline__ float bflo(u32 v) { return __uint_as_float(v << 16); }
__device__ __forceinline__ float bfhi(u32 v) { return __uint_as_float(v & 0xffff0000u); }

__device__ __forceinline__ void gld16(const void* g, void* l) {
  __builtin_amdgcn_global_load_lds(
      (const __attribute__((address_space(1))) void*)g,
      (__attribute__((address_space(3))) void*)l, 16, 0, 0);
}

// sum across each 16-lane row via DPP row_ror (pure VALU, no LDS pipe)
__device__ __forceinline__ float rowsum16(float p) {
  p += __int_as_float(__builtin_amdgcn_update_dpp(0, __float_as_int(p), 0x121, 0xf, 0xf, false));
  p += __int_as_float(__builtin_amdgcn_update_dpp(0, __float_as_int(p), 0x122, 0xf, 0xf, false));
  p += __int_as_float(__builtin_amdgcn_update_dpp(0, __float_as_int(p), 0x124, 0xf, 0xf, false));
  p += __int_as_float(__builtin_amdgcn_update_dpp(0, __float_as_int(p), 0x128, 0xf, 0xf, false));
  return p;
}

// ---------------------------------------------------------------------------
// bf16 MFMA GEMM: C[M,Nc] = A[M,K] @ W[Nc,K]^T (+bias).
// 128x128 tile, BK=32, 4 waves -> 64x64 each (4x4 of 16x16x32 MFMA).
// Double-buffered LDS: barrier -> prefetch tile k+1 (async gld16) -> MFMA on
// tile k. Loads get the whole compute phase to land; one barrier per iter.
// ---------------------------------------------------------------------------
__global__ __launch_bounds__(256) void gemm_mfma(
    const u16* __restrict__ A, int lda,
    const u16* __restrict__ W, int ldw,
    const float* __restrict__ bias,
    void* __restrict__ Cout, int ldc,
    int M, int Nc, int K, int c_bf16)
{
  __shared__ u16 Asm[2][128 * 32];
  __shared__ u16 Bsm[2][128 * 32];
  const int tid = threadIdx.x;
  const int wave = tid >> 6, lane = tid & 63;
  const int wm = (wave >> 1) << 6, wn = (wave & 1) << 6;
  const int bm = blockIdx.y * 128, bn = blockIdx.x * 128;

  f32x4 acc[4][4];
#pragma unroll
  for (int i = 0; i < 4; ++i)
#pragma unroll
    for (int j = 0; j < 4; ++j) acc[i][j] = (f32x4){0.f, 0.f, 0.f, 0.f};

  const int qr = lane >> 2;          // row within 16-row chunk
  const int qc = (lane & 3) << 3;    // k-offset (0,8,16,24)
  const int q0 = wave * 2, q1 = wave * 2 + 1;
  const int ra0 = bm + q0 * 16 + qr;
  const int ra1 = bm + q1 * 16 + qr;
  int rb0 = bn + q0 * 16 + qr; if (rb0 >= Nc) rb0 = Nc - 1;
  int rb1 = bn + q1 * 16 + qr; if (rb1 >= Nc) rb1 = Nc - 1;

  const u16* pa0 = A + (size_t)ra0 * lda + qc;
  const u16* pa1 = A + (size_t)ra1 * lda + qc;
  const u16* pb0 = W + (size_t)rb0 * ldw + qc;
  const u16* pb1 = W + (size_t)rb1 * ldw + qc;

  const int fm = lane & 15;
  const int fk = (lane >> 4) << 3;

  // stage tile 0 into buffer 0
  gld16(pa0, &Asm[0][q0 * 512]);
  gld16(pa1, &Asm[0][q1 * 512]);
  gld16(pb0, &Bsm[0][q0 * 512]);
  gld16(pb1, &Bsm[0][q1 * 512]);
  pa0 += 32; pa1 += 32; pb0 += 32; pb1 += 32;

  const int iters = K >> 5;
#pragma unroll 2
  for (int it = 0; it < iters; ++it) {
    const int cur = it & 1;
    __syncthreads();                    // drains vmcnt(0): tile `it` is in LDS
    if (it + 1 < iters) {
      const int nxt = cur ^ 1;
      gld16(pa0, &Asm[nxt][q0 * 512]);
      gld16(pa1, &Asm[nxt][q1 * 512]);
      gld16(pb0, &Bsm[nxt][q0 * 512]);
      gld16(pb1, &Bsm[nxt][q1 * 512]);
      pa0 += 32; pa1 += 32; pb0 += 32; pb1 += 32;
    }
    bf16x8 af[4], bfr[4];
#pragma unroll
    for (int i = 0; i < 4; ++i)
      af[i] = *(const bf16x8*)&Asm[cur][(wm + i * 16 + fm) * 32 + fk];
#pragma unroll
    for (int j = 0; j < 4; ++j)
      bfr[j] = *(const bf16x8*)&Bsm[cur][(wn + j * 16 + fm) * 32 + fk];
#pragma unroll
    for (int i = 0; i < 4; ++i)
#pragma unroll
      for (int j = 0; j < 4; ++j)
        acc[i][j] = __builtin_amdgcn_mfma_f32_16x16x32_bf16(af[i], bfr[j], acc[i][j], 0, 0, 0);
  }

  const int cn = lane & 15, cm = (lane >> 4) << 2;
#pragma unroll
  for (int j = 0; j < 4; ++j) {
    const int c = bn + wn + j * 16 + cn;
    if (c >= Nc) continue;
    const float bb = bias ? bias[c] : 0.f;
#pragma unroll
    for (int i = 0; i < 4; ++i) {
#pragma unroll
      for (int r = 0; r < 4; ++r) {
        const int m = bm + wm + i * 16 + cm + r;
        if (m >= M) continue;
        const float v = acc[i][j][r] + bb;
        if (c_bf16) ((u16*)Cout)[(size_t)m * ldc + c] = f2bf(v);
        else        ((float*)Cout)[(size_t)m * ldc + c] = v;
      }
    }
  }
}

// ---------------------------------------------------------------------------
// Setup / conversion kernels (once per launch; tiny)
// ---------------------------------------------------------------------------
__global__ void k_bias_sum(const float* __restrict__ b_ih,
                           const float* __restrict__ b_hh,
                           float* __restrict__ bsum) {
  int i = blockIdx.x * blockDim.x + threadIdx.x;
  if (i < 4 * HL) bsum[i] = b_ih[i] + b_hh[i];
}

__global__ void k_wcat_bf(const float* __restrict__ W_ih,
                          const float* __restrict__ W_hh,
                          u16* __restrict__ w) {
  int idx = blockIdx.x * blockDim.x + threadIdx.x;
  if (idx >= HC * KP1) return;
  int j = idx / KP1, k = idx - j * KP1;
  float v = 0.f;
  if (k < DD) v = W_ih[j * DD + k];
  else if (k < DD + HL) v = W_hh[j * HL + (k - DD)];
  w[idx] = f2bf(v);
}

__global__ void k_wlr1_bf(const float* __restrict__ Wl,
                          const float* __restrict__ Wr,
                          u16* __restrict__ w) {
  int idx = blockIdx.x * blockDim.x + threadIdx.x;
  if (idx >= 2 * HC * KP1) return;
  int j = idx / KP1, k = idx - j * KP1;
  const float* src = (j < HC) ? Wl : Wr;
  int jj = j & (HC - 1);
  float v = (k < DS + HL) ? src[jj * (DS + HL) + k] : 0.f;
  w[idx] = f2bf(v);
}

__global__ void k_wlr2_bf(const float* __restrict__ Wl,
                          const float* __restrict__ Wr,
                          u16* __restrict__ w) {
  int idx = blockIdx.x * blockDim.x + threadIdx.x;
  if (idx >= 2 * HC * HC) return;
  int j = idx >> 9, k = idx & (HC - 1);
  const float* src = (j < HC) ? Wl : Wr;
  int jj = j & (HC - 1);
  w[idx] = f2bf(src[jj * HC + k]);
}

__global__ void k_wp_bf(const float* __restrict__ Wp, u16* __restrict__ w) {
  int idx = blockIdx.x * blockDim.x + threadIdx.x;
  if (idx < EMB * HC) w[idx] = f2bf(Wp[idx]);
}

// packG1 static cols (once per launch)
__global__ void k_pack_static(const float* __restrict__ xs, u16* __restrict__ packG1) {
  int idx = blockIdx.x * blockDim.x + threadIdx.x;
  if (idx >= N_NODES * DS) return;
  int n = idx >> 4, k = idx & 15;
  packG1[(size_t)n * KP1 + k] = f2bf(xs[idx]);
}

// packXH dyn cols for t=0 only (later steps written by lstm_update)
__global__ void k_pack_dyn(const float* __restrict__ dyn, u16* __restrict__ packXH) {
  int idx = blockIdx.x * blockDim.x + threadIdx.x;
  if (idx >= N_NODES * DD) return;
  int n = idx >> 3, k = idx & 7;
  packXH[(size_t)n * KP1 + k] = f2bf(dyn[(size_t)n * (T_SEQ * DD) + k]);
}

// LSTM pointwise; writes h (bf16) into both GEMM inputs and next step's dyn cols
__global__ void lstm_update(const float* __restrict__ gates,
                            float* __restrict__ c,
                            u16* __restrict__ packXH, u16* __restrict__ packG1,
                            const float* __restrict__ dyn, int t_next) {
  int idx = blockIdx.x * blockDim.x + threadIdx.x;
  if (idx >= N_NODES * HL) return;
  int n = idx >> 7, j = idx & 127;
  const float* g = gates + (size_t)n * HC;
  float gi = g[j], gf = g[j + 128], gg = g[j + 256], go = g[j + 384];
  float si = 1.f / (1.f + __expf(-gi));
  float sf = 1.f / (1.f + __expf(-gf));
  float so = 1.f / (1.f + __expf(-go));
  float cn = sf * c[idx] + si * tanhf(gg);
  c[idx] = cn;
  u16 hb = f2bf(so * tanhf(cn));
  packXH[(size_t)n * KP1 + DD + j] = hb;
  packG1[(size_t)n * KP1 + DS + j] = hb;
  if (j < DD && t_next < T_SEQ)
    packXH[(size_t)n * KP1 + j] =
        f2bf(dyn[(size_t)n * (T_SEQ * DD) + t_next * DD + j]);
}

// ---------------------------------------------------------------------------
// CSR build (dst-sorted), rebuilt every launch
// ---------------------------------------------------------------------------
__global__ void k_deg(const int* __restrict__ ei, int* __restrict__ deg) {
  int e = blockIdx.x * blockDim.x + threadIdx.x;
  if (e >= EP) return;
  int d = (e < E_EDGES) ? ei[E_EDGES + e] : (e - E_EDGES);
  atomicAdd(&deg[d], 1);
}

__global__ __launch_bounds__(1024) void k_scan(const int* __restrict__ deg,
                                               int* __restrict__ rowstart) {
  __shared__ int buf[1024];
  __shared__ int carry_s;
  const int tid = threadIdx.x;
  if (tid == 0) carry_s = 0;
  __syncthreads();
  for (int base = 0; base < N_NODES; base += 1024) {
    int v = (base + tid < N_NODES) ? deg[base + tid] : 0;
    buf[tid] = v;
    __syncthreads();
    for (int off = 1; off < 1024; off <<= 1) {
      int add = (tid >= off) ? buf[tid - off] : 0;
      __syncthreads();
      buf[tid] += add;
      __syncthreads();
    }
    int incl = buf[tid];
    int carry = carry_s;
    if (base + tid < N_NODES) rowstart[base + tid] = carry + incl - v;
    __syncthreads();
    if (tid == 1023) carry_s = carry + incl;
    __syncthreads();
  }
  if (tid == 0) rowstart[N_NODES] = carry_s;
}

__global__ void k_fill(const int* __restrict__ ei,
                       const int* __restrict__ rowstart,
                       int* __restrict__ cursor, int* __restrict__ csr) {
  int e = blockIdx.x * blockDim.x + threadIdx.x;
  if (e >= EP) return;
  int s, d;
  if (e < E_EDGES) { s = ei[e]; d = ei[E_EDGES + e]; }
  else             { s = d = e - E_EDGES; }
  int pos = atomicAdd(&cursor[d], 1);
  csr[rowstart[d] + pos] = s;
}

// ---------------------------------------------------------------------------
// GATv2 edge softmax + aggregation v4. xlr bf16 [MP,1024] (xl | xr).
// One wave per dst; lane = 8 channels (uint4 gather); heads = 16-lane rows.
// DPP row_ror reduction (no LDS pipe); leaky dot via
// sum(att*leaky(e)) = 0.6*sum(att*e) + 0.4*sum(att*|e|), |e| = free modifier.
// No max subtraction (scores provably small; softmax shift-invariant).
// ---------------------------------------------------------------------------
__global__ __launch_bounds__(256) void gat_edge(
    const u16* __restrict__ xlr,
    const float* __restrict__ att, const float* __restrict__ bias,
    const int* __restrict__ rowstart, const int* __restrict__ csr,
    u16* __restrict__ outb)
{
  const int wave = threadIdx.x >> 6, lane = threadIdx.x & 63;
  const int d = blockIdx.x * 4 + wave;
  const int ch = lane * 8;                  // [0,512); head = lane>>4
  const uint4 vr = *(const uint4*)(xlr + (size_t)d * 1024 + 512 + ch);
  const float rxa0 = bflo(vr.x), rxa1 = bfhi(vr.x), rxa2 = bflo(vr.y), rxa3 = bfhi(vr.y);
  const float rxb0 = bflo(vr.z), rxb1 = bfhi(vr.z), rxb2 = bflo(vr.w), rxb3 = bfhi(vr.w);
  const float4 ava = *(const float4*)(att + ch);
  const float4 avb = *(const float4*)(att + ch + 4);
  const int row = rowstart[d], end = rowstart[d + 1];
  const char* __restrict__ xbase = (const char*)(xlr + ch);  // + (s<<11) bytes

  float l = 0.f;
  float a0 = 0.f, a1 = 0.f, a2 = 0.f, a3 = 0.f;
  float b0 = 0.f, b1 = 0.f, b2 = 0.f, b3 = 0.f;

#define GAT_STEP(v)                                                          \
  {                                                                          \
    const float xa0 = bflo((v).x), xa1 = bfhi((v).x);                        \
    const float xa2 = bflo((v).y), xa3 = bfhi((v).y);                        \
    const float xb0 = bflo((v).z), xb1 = bfhi((v).z);                        \
    const float xb2 = bflo((v).w), xb3 = bfhi((v).w);                        \
    const float e0 = xa0 + rxa0, e1 = xa1 + rxa1;                            \
    const float e2 = xa2 + rxa2, e3 = xa3 + rxa3;                            \
    const float f0 = xb0 + rxb0, f1 = xb1 + rxb1;                            \
    const float f2 = xb2 + rxb2, f3 = xb3 + rxb3;                            \
    float ps = e0 * ava.x;                                                   \
    ps = fmaf(e1, ava.y, ps); ps = fmaf(e2, ava.z, ps);                      \
    ps = fmaf(e3, ava.w, ps); ps = fmaf(f0, avb.x, ps);                      \
    ps = fmaf(f1, avb.y, ps); ps = fmaf(f2, avb.z, ps);                      \
    ps = fmaf(f3, avb.w, ps);                                                \
    float pa = fabsf(e0) * ava.x;                                            \
    pa = fmaf(fabsf(e1), ava.y, pa); pa = fmaf(fabsf(e2), ava.z, pa);        \
    pa = fmaf(fabsf(e3), ava.w, pa); pa = fmaf(fabsf(f0), avb.x, pa);        \
    pa = fmaf(fabsf(f1), avb.y, pa); pa = fmaf(fabsf(f2), avb.z, pa);        \
    pa = fmaf(fabsf(f3), avb.w, pa);                                         \
    float p = rowsum16(fmaf(0.6f, ps, 0.4f * pa));                           \
    const float w = __expf(p);                                               \
    l += w;                                                                  \
    a0 = fmaf(w, xa0, a0); a1 = fmaf(w, xa1, a1);                            \
    a2 = fmaf(w, xa2, a2); a3 = fmaf(w, xa3, a3);                            \
    b0 = fmaf(w, xb0, b0); b1 = fmaf(w, xb1, b1);                            \
    b2 = fmaf(w, xb2, b2); b3 = fmaf(w, xb3, b3);                            \
  }

  int i = row;
  for (; i + 1 < end; i += 2) {
    const u32 s0 = (u32)csr[i], s1 = (u32)csr[i + 1];
    const uint4 v0 = *(const uint4*)(xbase + (s0 << 11));
    const uint4 v1 = *(const uint4*)(xbase + (s1 << 11));
    GAT_STEP(v0);
    GAT_STEP(v1);
  }
  if (i < end) {
    const u32 s0 = (u32)csr[i];
    const uint4 v0 = *(const uint4*)(xbase + (s0 << 11));
    GAT_STEP(v0);
  }
#undef GAT_STEP

  const float inv = 1.f / l;
  const float4 ba = *(const float4*)(bias + ch);
  const float4 bb = *(const float4*)(bias + ch + 4);
  uint4 ov;
  ov.x = (u32)f2bf(fmaf(a0, inv, ba.x)) | ((u32)f2bf(fmaf(a1, inv, ba.y)) << 16);
  ov.y = (u32)f2bf(fmaf(a2, inv, ba.z)) | ((u32)f2bf(fmaf(a3, inv, ba.w)) << 16);
  ov.z = (u32)f2bf(fmaf(b0, inv, bb.x)) | ((u32)f2bf(fmaf(b1, inv, bb.y)) << 16);
  ov.w = (u32)f2bf(fmaf(b2, inv, bb.z)) | ((u32)f2bf(fmaf(b3, inv, bb.w)) << 16);
  *(uint4*)(outb + (size_t)d * HC + ch) = ov;
}

// ---------------------------------------------------------------------------
// BatchNorm stats (bf16 input): stats[0..HC)=sum, [HC..2HC)=sumsq
// ---------------------------------------------------------------------------
__global__ __launch_bounds__(256) void bn_stats(const u16* __restrict__ x,
                                                float* __restrict__ stats) {
  const int tid = threadIdx.x;
  const int rows_per = (N_NODES + gridDim.x - 1) / gridDim.x;
  const int r0 = blockIdx.x * rows_per;
  const int r1 = min(r0 + rows_per, N_NODES);
  const u32* xp = (const u32*)x;
  float s0 = 0.f, s1 = 0.f, q0 = 0.f, q1 = 0.f;
  for (int r = r0; r < r1; ++r) {
    const u32 v = xp[(size_t)r * 256 + tid];
    const float v0 = bflo(v), v1 = bfhi(v);
    s0 += v0; q0 += v0 * v0;
    s1 += v1; q1 += v1 * v1;
  }
  atomicAdd(&stats[2 * tid],          s0);
  atomicAdd(&stats[2 * tid + 1],      s1);
  atomicAdd(&stats[HC + 2 * tid],     q0);
  atomicAdd(&stats[HC + 2 * tid + 1], q1);
}

__global__ void bn_apply(const u16* __restrict__ x, const float* __restrict__ stats,
                         const float* __restrict__ gamma, const float* __restrict__ beta,
                         u16* __restrict__ outb) {
  int idx = blockIdx.x * blockDim.x + threadIdx.x;
  if (idx >= N_NODES * (HC / 2)) return;
  const int cc = idx & (HC / 2 - 1);
  const int c0 = cc * 2, c1 = c0 + 1;
  const u32 v = ((const u32*)x)[idx];
  const float mean0 = stats[c0] * (1.f / N_NODES);
  const float mean1 = stats[c1] * (1.f / N_NODES);
  const float inv0 = rsqrtf(stats[HC + c0] * (1.f / N_NODES) - mean0 * mean0 + 1e-5f);
  const float inv1 = rsqrtf(stats[HC + c1] * (1.f / N_NODES) - mean1 * mean1 + 1e-5f);
  float z0 = (bflo(v) - mean0) * inv0 * gamma[c0] + beta[c0];
  float z1 = (bfhi(v) - mean1) * inv1 * gamma[c1] + beta[c1];
  z0 = z0 > 0.f ? z0 : 0.f;
  z1 = z1 > 0.f ? z1 : 0.f;
  ((u32*)outb)[idx] = (u32)f2bf(z0) | ((u32)f2bf(z1) << 16);
}

// ---------------------------------------------------------------------------
extern "C" void kernel_launch(void* const* d_in, const int* in_sizes, int n_in,
                              void* d_out, int out_size, void* d_ws, size_t ws_size,
                              hipStream_t stream) {
  const float* x_static = (const float*)d_in[0];
  const float* dyn      = (const float*)d_in[1];
  const int*   ei       = (const int*)d_in[2];
  const float* W_ih     = (const float*)d_in[3];
  const float* W_hh     = (const float*)d_in[4];
  const float* b_ih     = (const float*)d_in[5];
  const float* b_hh     = (const float*)d_in[6];
  const float* Wl1      = (const float*)d_in[7];
  const float* Wr1      = (const float*)d_in[8];
  const float* att1     = (const float*)d_in[9];
  const float* bg1      = (const float*)d_in[10];
  const float* Wl2      = (const float*)d_in[11];
  const float* Wr2      = (const float*)d_in[12];
  const float* att2     = (const float*)d_in[13];
  const float* bg2      = (const float*)d_in[14];
  const float* gamma1   = (const float*)d_in[15];
  const float* beta1    = (const float*)d_in[16];
  const float* gamma2   = (const float*)d_in[17];
  const float* beta2    = (const float*)d_in[18];
  const float* Wp       = (const float*)d_in[19];
  const float* bp       = (const float*)d_in[20];
  float* out = (float*)d_out;

  // ---- workspace carve (float units) ----
  float* ws = (float*)d_ws;
  size_t o = 0;
  float* c     = ws + o; o += (size_t)MP * HL;
  float* gates = ws + o; o += (size_t)MP * HC;
  float* stats = ws + o; o += 4 * HC;
  float* bsum  = ws + o; o += 4 * HL;
  u16* packXH  = (u16*)(ws + o); o += (size_t)MP * KP1 / 2;
  u16* packG1  = (u16*)(ws + o); o += (size_t)MP * KP1 / 2;
  u16* xlr     = (u16*)(ws + o); o += (size_t)MP * 1024 / 2;
  u16* gout    = (u16*)(ws + o); o += (size_t)MP * HC / 2;
  u16* aggb    = (u16*)(ws + o); o += (size_t)MP * HC / 2;
  u16* wcat_bf = (u16*)(ws + o); o += (size_t)HC * KP1 / 2;
  u16* wlr1_bf = (u16*)(ws + o); o += (size_t)2 * HC * KP1 / 2;
  u16* wlr2_bf = (u16*)(ws + o); o += (size_t)2 * HC * HC / 2;
  u16* wp_bf   = (u16*)(ws + o); o += (size_t)EMB * HC / 2;
  int* deg      = (int*)(ws + o); o += N_NODES;
  int* cursor   = (int*)(ws + o); o += N_NODES;
  int* rowstart = (int*)(ws + o); o += N_NODES + 64;
  int* csr      = (int*)(ws + o); o += EP;

  // ---- per-launch init ----
  hipMemsetAsync(deg,    0, N_NODES * sizeof(int), stream);
  hipMemsetAsync(cursor, 0, N_NODES * sizeof(int), stream);
  hipMemsetAsync(c,      0, (size_t)MP * HL * sizeof(float), stream);
  hipMemsetAsync(packXH, 0, (size_t)MP * KP1 * sizeof(u16), stream);  // h=0 + pads
  hipMemsetAsync(packG1, 0, (size_t)MP * KP1 * sizeof(u16), stream);
  hipMemsetAsync(aggb,   0, (size_t)MP * HC * sizeof(u16), stream);   // pad rows

  k_bias_sum<<<2, 256, 0, stream>>>(b_ih, b_hh, bsum);
  k_wcat_bf<<<(HC * KP1 + 255) / 256, 256, 0, stream>>>(W_ih, W_hh, wcat_bf);
  k_wlr1_bf<<<(2 * HC * KP1 + 255) / 256, 256, 0, stream>>>(Wl1, Wr1, wlr1_bf);
  k_wlr2_bf<<<(2 * HC * HC + 255) / 256, 256, 0, stream>>>(Wl2, Wr2, wlr2_bf);
  k_wp_bf<<<(EMB * HC + 255) / 256, 256, 0, stream>>>(Wp, wp_bf);
  k_pack_static<<<(N_NODES * DS + 255) / 256, 256, 0, stream>>>(x_static, packG1);
  k_pack_dyn<<<(N_NODES * DD + 255) / 256, 256, 0, stream>>>(dyn, packXH);
  k_deg<<<(EP + 255) / 256, 256, 0, stream>>>(ei, deg);
  k_scan<<<1, 1024, 0, stream>>>(deg, rowstart);
  k_fill<<<(EP + 255) / 256, 256, 0, stream>>>(ei, rowstart, cursor, csr);

  const int GY = MP / 128;                       // 157
  const dim3 g_gates(HC / 128, GY);              // (4,157)
  const dim3 g_xlr(2 * HC / 128, GY);            // (8,157)
  const dim3 g_proj(1, GY);                      // (1,157)

  for (int t = 0; t < T_SEQ; ++t) {
    // ---- LSTM step t ----
    gemm_mfma<<<g_gates, 256, 0, stream>>>(packXH, KP1, wcat_bf, KP1, bsum,
                                           gates, HC, MP, HC, KP1, 0);
    lstm_update<<<(N_NODES * HL + 255) / 256, 256, 0, stream>>>(
        gates, c, packXH, packG1, dyn, t + 1);

    hipMemsetAsync(stats, 0, 4 * HC * sizeof(float), stream);

    // ---- GAT layer 1 ----
    gemm_mfma<<<g_xlr, 256, 0, stream>>>(packG1, KP1, wlr1_bf, KP1, nullptr,
                                         xlr, 1024, MP, 2 * HC, KP1, 1);
    gat_edge<<<N_NODES / 4, 256, 0, stream>>>(xlr, att1, bg1, rowstart, csr, gout);
    bn_stats<<<500, 256, 0, stream>>>(gout, stats);
    bn_apply<<<(N_NODES * HC / 2 + 255) / 256, 256, 0, stream>>>(gout, stats,
                                                                 gamma1, beta1, aggb);

    // ---- GAT layer 2 ----
    gemm_mfma<<<g_xlr, 256, 0, stream>>>(aggb, HC, wlr2_bf, HC, nullptr,
                                         xlr, 1024, MP, 2 * HC, HC, 1);
    gat_edge<<<N_NODES / 4, 256, 0, stream>>>(xlr, att2, bg2, rowstart, csr, gout);
    bn_stats<<<500, 256, 0, stream>>>(gout, stats + 2 * HC);
    bn_apply<<<(N_NODES * HC / 2 + 255) / 256, 256, 0, stream>>>(gout, stats + 2 * HC,
                                                                 gamma2, beta2, aggb);

    // ---- output projection into out[n][t][:] ----
    gemm_mfma<<<g_proj, 256, 0, stream>>>(aggb, HC, wp_bf, HC, bp,
                                          out + t * EMB, T_SEQ * EMB,
                                          N_NODES, EMB, HC, 0);
  }
}

// Round 6
// 2500.764 us; speedup vs baseline: 3.0020x; 1.1581x over previous
//
#include <hip/hip_runtime.h>
#include <math.h>

typedef unsigned short u16;
typedef unsigned int u32;

#define N_NODES 20000
#define MP      20480            // N padded to multiple of 1024 (128 x 8 XCD groups)
#define T_SEQ   8
#define DS      16
#define DD      8
#define E_EDGES 320000
#define HL      128
#define GH      4
#define GC      128
#define HC      512
#define EMB     64
#define KP1     160              // padded K for LSTM (136) and GAT1 (144)
#define EP      (E_EDGES + N_NODES)

typedef __attribute__((ext_vector_type(8))) short bf16x8;
typedef __attribute__((ext_vector_type(4))) float f32x4;

__device__ __forceinline__ u16 f2bf(float f) {
  u32 u = __float_as_uint(f);
  u += 0x7fff + ((u >> 16) & 1);   // RNE (inputs are finite)
  return (u16)(u >> 16);
}
__device__ __forceinline__ float bflo(u32 v) { return __uint_as_float(v << 16); }
__device__ __forceinline__ float bfhi(u32 v) { return __uint_as_float(v & 0xffff0000u); }

__device__ __forceinline__ void gld16(const void* g, void* l) {
  __builtin_amdgcn_global_load_lds(
      (const __attribute__((address_space(1))) void*)g,
      (__attribute__((address_space(3))) void*)l, 16, 0, 0);
}

// sum across each 16-lane row via DPP row_ror (pure VALU, no LDS pipe)
__device__ __forceinline__ float rowsum16(float p) {
  p += __int_as_float(__builtin_amdgcn_update_dpp(0, __float_as_int(p), 0x121, 0xf, 0xf, false));
  p += __int_as_float(__builtin_amdgcn_update_dpp(0, __float_as_int(p), 0x122, 0xf, 0xf, false));
  p += __int_as_float(__builtin_amdgcn_update_dpp(0, __float_as_int(p), 0x124, 0xf, 0xf, false));
  p += __int_as_float(__builtin_amdgcn_update_dpp(0, __float_as_int(p), 0x128, 0xf, 0xf, false));
  return p;
}

// ---------------------------------------------------------------------------
// bf16 MFMA GEMM: C[M,Nc] = A[M,K] @ W[Nc,K]^T (+bias).
// 128x128 tile, BK=32, double-buffered LDS (prefetch-after-barrier).
// 1-D grid with XCD-aware swizzle: all column-blocks of one row-block land on
// the same XCD (id%8) so the A-tile is fetched from HBM once, then L2-hot.
// bf16 output goes through an LDS-staged, fully-coalesced uint4 epilogue
// (reuses the 32 KB staging LDS); fp32 output keeps the direct store path.
// ---------------------------------------------------------------------------
__global__ __launch_bounds__(256) void gemm_mfma(
    const u16* __restrict__ A, int lda,
    const u16* __restrict__ W, int ldw,
    const float* __restrict__ bias,
    void* __restrict__ Cout, int ldc,
    int M, int Nc, int K, int c_bf16, int gxs)
{
  __shared__ u16 smem[16384];            // [0,8K): A dbuf, [8K,16K): B dbuf; epilogue: C tile
  u16* Asm = smem;                       // Asm[buf*4096 + idx]
  u16* Bsm = smem + 8192;

  const int tid = threadIdx.x;
  const int wave = tid >> 6, lane = tid & 63;
  const int wm = (wave >> 1) << 6, wn = (wave & 1) << 6;

  // XCD swizzle
  const u32 id = blockIdx.x;
  const int xcd = id & 7;
  const u32 sl = id >> 3;
  const int GXm = (1 << gxs) - 1;
  const int bn = (int)(sl & GXm) << 7;
  const int bm = (xcd + (int)((sl >> gxs) << 3)) << 7;

  f32x4 acc[4][4];
#pragma unroll
  for (int i = 0; i < 4; ++i)
#pragma unroll
    for (int j = 0; j < 4; ++j) acc[i][j] = (f32x4){0.f, 0.f, 0.f, 0.f};

  const int qr = lane >> 2;          // row within 16-row chunk
  const int qc = (lane & 3) << 3;    // k-offset (0,8,16,24)
  const int q0 = wave * 2, q1 = wave * 2 + 1;
  const int ra0 = bm + q0 * 16 + qr;
  const int ra1 = bm + q1 * 16 + qr;
  int rb0 = bn + q0 * 16 + qr; if (rb0 >= Nc) rb0 = Nc - 1;
  int rb1 = bn + q1 * 16 + qr; if (rb1 >= Nc) rb1 = Nc - 1;

  const u16* pa0 = A + (size_t)ra0 * lda + qc;
  const u16* pa1 = A + (size_t)ra1 * lda + qc;
  const u16* pb0 = W + (size_t)rb0 * ldw + qc;
  const u16* pb1 = W + (size_t)rb1 * ldw + qc;

  const int fm = lane & 15;
  const int fk = (lane >> 4) << 3;

  // stage tile 0 into buffer 0
  gld16(pa0, &Asm[q0 * 512]);
  gld16(pa1, &Asm[q1 * 512]);
  gld16(pb0, &Bsm[q0 * 512]);
  gld16(pb1, &Bsm[q1 * 512]);
  pa0 += 32; pa1 += 32; pb0 += 32; pb1 += 32;

  const int iters = K >> 5;
#pragma unroll 2
  for (int it = 0; it < iters; ++it) {
    const int cur = (it & 1) * 4096;
    __syncthreads();                    // tile `it` now in LDS
    if (it + 1 < iters) {
      const int nxt = cur ^ 4096;
      gld16(pa0, &Asm[nxt + q0 * 512]);
      gld16(pa1, &Asm[nxt + q1 * 512]);
      gld16(pb0, &Bsm[nxt + q0 * 512]);
      gld16(pb1, &Bsm[nxt + q1 * 512]);
      pa0 += 32; pa1 += 32; pb0 += 32; pb1 += 32;
    }
    bf16x8 af[4], bfr[4];
#pragma unroll
    for (int i = 0; i < 4; ++i)
      af[i] = *(const bf16x8*)&Asm[cur + (wm + i * 16 + fm) * 32 + fk];
#pragma unroll
    for (int j = 0; j < 4; ++j)
      bfr[j] = *(const bf16x8*)&Bsm[cur + (wn + j * 16 + fm) * 32 + fk];
#pragma unroll
    for (int i = 0; i < 4; ++i)
#pragma unroll
      for (int j = 0; j < 4; ++j)
        acc[i][j] = __builtin_amdgcn_mfma_f32_16x16x32_bf16(af[i], bfr[j], acc[i][j], 0, 0, 0);
  }

  // C/D layout: col = lane&15, row = (lane>>4)*4 + reg
  const int cn = lane & 15, cm = (lane >> 4) << 2;
  if (c_bf16) {
    // stage C tile (128x128 bf16 = 32 KB) into LDS, then coalesced stores
    __syncthreads();                    // all LDS reads of the K-loop done
#pragma unroll
    for (int j = 0; j < 4; ++j) {
      const int c = wn + j * 16 + cn;
      const float bb = bias ? bias[bn + c] : 0.f;
#pragma unroll
      for (int i = 0; i < 4; ++i) {
#pragma unroll
        for (int r = 0; r < 4; ++r)
          smem[(wm + i * 16 + cm + r) * 128 + c] = f2bf(acc[i][j][r] + bb);
      }
    }
    __syncthreads();
    // 2048 16-byte chunks, fully coalesced (1 KB per wave-instr)
    u16* outc = (u16*)Cout;
#pragma unroll
    for (int k = 0; k < 8; ++k) {
      const int idx = tid + k * 256;
      const int r = idx >> 4, cc = (idx & 15) << 3;
      *(uint4*)(outc + (size_t)(bm + r) * ldc + bn + cc) = *(const uint4*)&smem[r * 128 + cc];
    }
  } else {
#pragma unroll
    for (int j = 0; j < 4; ++j) {
      const int c = bn + wn + j * 16 + cn;
      if (c >= Nc) continue;
      const float bb = bias ? bias[c] : 0.f;
#pragma unroll
      for (int i = 0; i < 4; ++i) {
#pragma unroll
        for (int r = 0; r < 4; ++r) {
          const int m = bm + wm + i * 16 + cm + r;
          if (m >= M) continue;
          ((float*)Cout)[(size_t)m * ldc + c] = acc[i][j][r] + bb;
        }
      }
    }
  }
}

// ---------------------------------------------------------------------------
// Setup / conversion kernels (once per launch; tiny)
// ---------------------------------------------------------------------------
__global__ void k_bias_sum(const float* __restrict__ b_ih,
                           const float* __restrict__ b_hh,
                           float* __restrict__ bsum) {
  int i = blockIdx.x * blockDim.x + threadIdx.x;
  if (i < 4 * HL) bsum[i] = b_ih[i] + b_hh[i];
}

__global__ void k_wcat_bf(const float* __restrict__ W_ih,
                          const float* __restrict__ W_hh,
                          u16* __restrict__ w) {
  int idx = blockIdx.x * blockDim.x + threadIdx.x;
  if (idx >= HC * KP1) return;
  int j = idx / KP1, k = idx - j * KP1;
  float v = 0.f;
  if (k < DD) v = W_ih[j * DD + k];
  else if (k < DD + HL) v = W_hh[j * HL + (k - DD)];
  w[idx] = f2bf(v);
}

__global__ void k_wlr1_bf(const float* __restrict__ Wl,
                          const float* __restrict__ Wr,
                          u16* __restrict__ w) {
  int idx = blockIdx.x * blockDim.x + threadIdx.x;
  if (idx >= 2 * HC * KP1) return;
  int j = idx / KP1, k = idx - j * KP1;
  const float* src = (j < HC) ? Wl : Wr;
  int jj = j & (HC - 1);
  float v = (k < DS + HL) ? src[jj * (DS + HL) + k] : 0.f;
  w[idx] = f2bf(v);
}

__global__ void k_wlr2_bf(const float* __restrict__ Wl,
                          const float* __restrict__ Wr,
                          u16* __restrict__ w) {
  int idx = blockIdx.x * blockDim.x + threadIdx.x;
  if (idx >= 2 * HC * HC) return;
  int j = idx >> 9, k = idx & (HC - 1);
  const float* src = (j < HC) ? Wl : Wr;
  int jj = j & (HC - 1);
  w[idx] = f2bf(src[jj * HC + k]);
}

__global__ void k_wp_bf(const float* __restrict__ Wp, u16* __restrict__ w) {
  int idx = blockIdx.x * blockDim.x + threadIdx.x;
  if (idx < EMB * HC) w[idx] = f2bf(Wp[idx]);
}

// packG1 static cols (once per launch)
__global__ void k_pack_static(const float* __restrict__ xs, u16* __restrict__ packG1) {
  int idx = blockIdx.x * blockDim.x + threadIdx.x;
  if (idx >= N_NODES * DS) return;
  int n = idx >> 4, k = idx & 15;
  packG1[(size_t)n * KP1 + k] = f2bf(xs[idx]);
}

// packXH dyn cols for t=0 only (later steps written by lstm_update)
__global__ void k_pack_dyn(const float* __restrict__ dyn, u16* __restrict__ packXH) {
  int idx = blockIdx.x * blockDim.x + threadIdx.x;
  if (idx >= N_NODES * DD) return;
  int n = idx >> 3, k = idx & 7;
  packXH[(size_t)n * KP1 + k] = f2bf(dyn[(size_t)n * (T_SEQ * DD) + k]);
}

// LSTM pointwise; writes h (bf16) into both GEMM inputs and next step's dyn cols
__global__ void lstm_update(const float* __restrict__ gates,
                            float* __restrict__ c,
                            u16* __restrict__ packXH, u16* __restrict__ packG1,
                            const float* __restrict__ dyn, int t_next) {
  int idx = blockIdx.x * blockDim.x + threadIdx.x;
  if (idx >= N_NODES * HL) return;
  int n = idx >> 7, j = idx & 127;
  const float* g = gates + (size_t)n * HC;
  float gi = g[j], gf = g[j + 128], gg = g[j + 256], go = g[j + 384];
  float si = 1.f / (1.f + __expf(-gi));
  float sf = 1.f / (1.f + __expf(-gf));
  float so = 1.f / (1.f + __expf(-go));
  float cn = sf * c[idx] + si * tanhf(gg);
  c[idx] = cn;
  u16 hb = f2bf(so * tanhf(cn));
  packXH[(size_t)n * KP1 + DD + j] = hb;
  packG1[(size_t)n * KP1 + DS + j] = hb;
  if (j < DD && t_next < T_SEQ)
    packXH[(size_t)n * KP1 + j] =
        f2bf(dyn[(size_t)n * (T_SEQ * DD) + t_next * DD + j]);
}

// ---------------------------------------------------------------------------
// CSR build (dst-sorted), rebuilt every launch
// ---------------------------------------------------------------------------
__global__ void k_deg(const int* __restrict__ ei, int* __restrict__ deg) {
  int e = blockIdx.x * blockDim.x + threadIdx.x;
  if (e >= EP) return;
  int d = (e < E_EDGES) ? ei[E_EDGES + e] : (e - E_EDGES);
  atomicAdd(&deg[d], 1);
}

__global__ __launch_bounds__(1024) void k_scan(const int* __restrict__ deg,
                                               int* __restrict__ rowstart) {
  __shared__ int buf[1024];
  __shared__ int carry_s;
  const int tid = threadIdx.x;
  if (tid == 0) carry_s = 0;
  __syncthreads();
  for (int base = 0; base < N_NODES; base += 1024) {
    int v = (base + tid < N_NODES) ? deg[base + tid] : 0;
    buf[tid] = v;
    __syncthreads();
    for (int off = 1; off < 1024; off <<= 1) {
      int add = (tid >= off) ? buf[tid - off] : 0;
      __syncthreads();
      buf[tid] += add;
      __syncthreads();
    }
    int incl = buf[tid];
    int carry = carry_s;
    if (base + tid < N_NODES) rowstart[base + tid] = carry + incl - v;
    __syncthreads();
    if (tid == 1023) carry_s = carry + incl;
    __syncthreads();
  }
  if (tid == 0) rowstart[N_NODES] = carry_s;
}

__global__ void k_fill(const int* __restrict__ ei,
                       const int* __restrict__ rowstart,
                       int* __restrict__ cursor, int* __restrict__ csr) {
  int e = blockIdx.x * blockDim.x + threadIdx.x;
  if (e >= EP) return;
  int s, d;
  if (e < E_EDGES) { s = ei[e]; d = ei[E_EDGES + e]; }
  else             { s = d = e - E_EDGES; }
  int pos = atomicAdd(&cursor[d], 1);
  csr[rowstart[d] + pos] = s;
}

// ---------------------------------------------------------------------------
// GATv2 edge softmax + aggregation v5. xlr bf16 [MP,1024] (xl | xr).
// One wave per dst; lane = 8 channels (uint4 gather); heads = 16-lane rows.
// 4-edge software pipeline (4 gathers in flight). DPP reduction; leaky via
// 0.6*sum(att*e) + 0.4*sum(att*|e|). No max subtraction (scores small).
// ---------------------------------------------------------------------------
__global__ __launch_bounds__(256) void gat_edge(
    const u16* __restrict__ xlr,
    const float* __restrict__ att, const float* __restrict__ bias,
    const int* __restrict__ rowstart, const int* __restrict__ csr,
    u16* __restrict__ outb)
{
  const int wave = threadIdx.x >> 6, lane = threadIdx.x & 63;
  const int d = blockIdx.x * 4 + wave;
  const int ch = lane * 8;                  // [0,512); head = lane>>4
  const uint4 vr = *(const uint4*)(xlr + (size_t)d * 1024 + 512 + ch);
  const float rxa0 = bflo(vr.x), rxa1 = bfhi(vr.x), rxa2 = bflo(vr.y), rxa3 = bfhi(vr.y);
  const float rxb0 = bflo(vr.z), rxb1 = bfhi(vr.z), rxb2 = bflo(vr.w), rxb3 = bfhi(vr.w);
  const float4 ava = *(const float4*)(att + ch);
  const float4 avb = *(const float4*)(att + ch + 4);
  const int row = rowstart[d], end = rowstart[d + 1];
  const char* __restrict__ xbase = (const char*)(xlr + ch);  // + (s<<11) bytes

  float l = 0.f;
  float a0 = 0.f, a1 = 0.f, a2 = 0.f, a3 = 0.f;
  float b0 = 0.f, b1 = 0.f, b2 = 0.f, b3 = 0.f;

#define GAT_STEP(v)                                                          \
  {                                                                          \
    const float xa0 = bflo((v).x), xa1 = bfhi((v).x);                        \
    const float xa2 = bflo((v).y), xa3 = bfhi((v).y);                        \
    const float xb0 = bflo((v).z), xb1 = bfhi((v).z);                        \
    const float xb2 = bflo((v).w), xb3 = bfhi((v).w);                        \
    const float e0 = xa0 + rxa0, e1 = xa1 + rxa1;                            \
    const float e2 = xa2 + rxa2, e3 = xa3 + rxa3;                            \
    const float f0 = xb0 + rxb0, f1 = xb1 + rxb1;                            \
    const float f2 = xb2 + rxb2, f3 = xb3 + rxb3;                            \
    float ps = e0 * ava.x;                                                   \
    ps = fmaf(e1, ava.y, ps); ps = fmaf(e2, ava.z, ps);                      \
    ps = fmaf(e3, ava.w, ps); ps = fmaf(f0, avb.x, ps);                      \
    ps = fmaf(f1, avb.y, ps); ps = fmaf(f2, avb.z, ps);                      \
    ps = fmaf(f3, avb.w, ps);                                                \
    float pa = fabsf(e0) * ava.x;                                            \
    pa = fmaf(fabsf(e1), ava.y, pa); pa = fmaf(fabsf(e2), ava.z, pa);        \
    pa = fmaf(fabsf(e3), ava.w, pa); pa = fmaf(fabsf(f0), avb.x, pa);        \
    pa = fmaf(fabsf(f1), avb.y, pa); pa = fmaf(fabsf(f2), avb.z, pa);        \
    pa = fmaf(fabsf(f3), avb.w, pa);                                         \
    float p = rowsum16(fmaf(0.6f, ps, 0.4f * pa));                           \
    const float w = __expf(p);                                               \
    l += w;                                                                  \
    a0 = fmaf(w, xa0, a0); a1 = fmaf(w, xa1, a1);                            \
    a2 = fmaf(w, xa2, a2); a3 = fmaf(w, xa3, a3);                            \
    b0 = fmaf(w, xb0, b0); b1 = fmaf(w, xb1, b1);                            \
    b2 = fmaf(w, xb2, b2); b3 = fmaf(w, xb3, b3);                            \
  }

  int i = row;
  for (; i + 3 < end; i += 4) {
    const u32 s0 = (u32)csr[i],     s1 = (u32)csr[i + 1];
    const u32 s2 = (u32)csr[i + 2], s3 = (u32)csr[i + 3];
    const uint4 v0 = *(const uint4*)(xbase + (s0 << 11));
    const uint4 v1 = *(const uint4*)(xbase + (s1 << 11));
    const uint4 v2 = *(const uint4*)(xbase + (s2 << 11));
    const uint4 v3 = *(const uint4*)(xbase + (s3 << 11));
    GAT_STEP(v0);
    GAT_STEP(v1);
    GAT_STEP(v2);
    GAT_STEP(v3);
  }
  for (; i < end; ++i) {
    const u32 s0 = (u32)csr[i];
    const uint4 v0 = *(const uint4*)(xbase + (s0 << 11));
    GAT_STEP(v0);
  }
#undef GAT_STEP

  const float inv = 1.f / l;
  const float4 ba = *(const float4*)(bias + ch);
  const float4 bb = *(const float4*)(bias + ch + 4);
  uint4 ov;
  ov.x = (u32)f2bf(fmaf(a0, inv, ba.x)) | ((u32)f2bf(fmaf(a1, inv, ba.y)) << 16);
  ov.y = (u32)f2bf(fmaf(a2, inv, ba.z)) | ((u32)f2bf(fmaf(a3, inv, ba.w)) << 16);
  ov.z = (u32)f2bf(fmaf(b0, inv, bb.x)) | ((u32)f2bf(fmaf(b1, inv, bb.y)) << 16);
  ov.w = (u32)f2bf(fmaf(b2, inv, bb.z)) | ((u32)f2bf(fmaf(b3, inv, bb.w)) << 16);
  *(uint4*)(outb + (size_t)d * HC + ch) = ov;
}

// ---------------------------------------------------------------------------
// BatchNorm stats (bf16 input): stats[0..HC)=sum, [HC..2HC)=sumsq
// ---------------------------------------------------------------------------
__global__ __launch_bounds__(256) void bn_stats(const u16* __restrict__ x,
                                                float* __restrict__ stats) {
  const int tid = threadIdx.x;
  const int rows_per = (N_NODES + gridDim.x - 1) / gridDim.x;
  const int r0 = blockIdx.x * rows_per;
  const int r1 = min(r0 + rows_per, N_NODES);
  const u32* xp = (const u32*)x;
  float s0 = 0.f, s1 = 0.f, q0 = 0.f, q1 = 0.f;
  for (int r = r0; r < r1; ++r) {
    const u32 v = xp[(size_t)r * 256 + tid];
    const float v0 = bflo(v), v1 = bfhi(v);
    s0 += v0; q0 += v0 * v0;
    s1 += v1; q1 += v1 * v1;
  }
  atomicAdd(&stats[2 * tid],          s0);
  atomicAdd(&stats[2 * tid + 1],      s1);
  atomicAdd(&stats[HC + 2 * tid],     q0);
  atomicAdd(&stats[HC + 2 * tid + 1], q1);
}

__global__ void bn_apply(const u16* __restrict__ x, const float* __restrict__ stats,
                         const float* __restrict__ gamma, const float* __restrict__ beta,
                         u16* __restrict__ outb) {
  int idx = blockIdx.x * blockDim.x + threadIdx.x;
  if (idx >= N_NODES * (HC / 2)) return;
  const int cc = idx & (HC / 2 - 1);
  const int c0 = cc * 2, c1 = c0 + 1;
  const u32 v = ((const u32*)x)[idx];
  const float mean0 = stats[c0] * (1.f / N_NODES);
  const float mean1 = stats[c1] * (1.f / N_NODES);
  const float inv0 = rsqrtf(stats[HC + c0] * (1.f / N_NODES) - mean0 * mean0 + 1e-5f);
  const float inv1 = rsqrtf(stats[HC + c1] * (1.f / N_NODES) - mean1 * mean1 + 1e-5f);
  float z0 = (bflo(v) - mean0) * inv0 * gamma[c0] + beta[c0];
  float z1 = (bfhi(v) - mean1) * inv1 * gamma[c1] + beta[c1];
  z0 = z0 > 0.f ? z0 : 0.f;
  z1 = z1 > 0.f ? z1 : 0.f;
  ((u32*)outb)[idx] = (u32)f2bf(z0) | ((u32)f2bf(z1) << 16);
}

// ---------------------------------------------------------------------------
extern "C" void kernel_launch(void* const* d_in, const int* in_sizes, int n_in,
                              void* d_out, int out_size, void* d_ws, size_t ws_size,
                              hipStream_t stream) {
  const float* x_static = (const float*)d_in[0];
  const float* dyn      = (const float*)d_in[1];
  const int*   ei       = (const int*)d_in[2];
  const float* W_ih     = (const float*)d_in[3];
  const float* W_hh     = (const float*)d_in[4];
  const float* b_ih     = (const float*)d_in[5];
  const float* b_hh     = (const float*)d_in[6];
  const float* Wl1      = (const float*)d_in[7];
  const float* Wr1      = (const float*)d_in[8];
  const float* att1     = (const float*)d_in[9];
  const float* bg1      = (const float*)d_in[10];
  const float* Wl2      = (const float*)d_in[11];
  const float* Wr2      = (const float*)d_in[12];
  const float* att2     = (const float*)d_in[13];
  const float* bg2      = (const float*)d_in[14];
  const float* gamma1   = (const float*)d_in[15];
  const float* beta1    = (const float*)d_in[16];
  const float* gamma2   = (const float*)d_in[17];
  const float* beta2    = (const float*)d_in[18];
  const float* Wp       = (const float*)d_in[19];
  const float* bp       = (const float*)d_in[20];
  float* out = (float*)d_out;

  // ---- workspace carve (float units) ----
  float* ws = (float*)d_ws;
  size_t o = 0;
  float* c     = ws + o; o += (size_t)MP * HL;
  float* gates = ws + o; o += (size_t)MP * HC;
  float* stats = ws + o; o += 4 * HC;
  float* bsum  = ws + o; o += 4 * HL;
  u16* packXH  = (u16*)(ws + o); o += (size_t)MP * KP1 / 2;
  u16* packG1  = (u16*)(ws + o); o += (size_t)MP * KP1 / 2;
  u16* xlr     = (u16*)(ws + o); o += (size_t)MP * 1024 / 2;
  u16* gout    = (u16*)(ws + o); o += (size_t)MP * HC / 2;
  u16* aggb    = (u16*)(ws + o); o += (size_t)MP * HC / 2;
  u16* wcat_bf = (u16*)(ws + o); o += (size_t)HC * KP1 / 2;
  u16* wlr1_bf = (u16*)(ws + o); o += (size_t)2 * HC * KP1 / 2;
  u16* wlr2_bf = (u16*)(ws + o); o += (size_t)2 * HC * HC / 2;
  u16* wp_bf   = (u16*)(ws + o); o += (size_t)EMB * HC / 2;
  int* deg      = (int*)(ws + o); o += N_NODES;
  int* cursor   = (int*)(ws + o); o += N_NODES;
  int* rowstart = (int*)(ws + o); o += N_NODES + 64;
  int* csr      = (int*)(ws + o); o += EP;

  // ---- per-launch init ----
  hipMemsetAsync(deg,    0, N_NODES * sizeof(int), stream);
  hipMemsetAsync(cursor, 0, N_NODES * sizeof(int), stream);
  hipMemsetAsync(c,      0, (size_t)MP * HL * sizeof(float), stream);
  hipMemsetAsync(packXH, 0, (size_t)MP * KP1 * sizeof(u16), stream);  // h=0 + pads
  hipMemsetAsync(packG1, 0, (size_t)MP * KP1 * sizeof(u16), stream);
  hipMemsetAsync(aggb,   0, (size_t)MP * HC * sizeof(u16), stream);   // pad rows

  k_bias_sum<<<2, 256, 0, stream>>>(b_ih, b_hh, bsum);
  k_wcat_bf<<<(HC * KP1 + 255) / 256, 256, 0, stream>>>(W_ih, W_hh, wcat_bf);
  k_wlr1_bf<<<(2 * HC * KP1 + 255) / 256, 256, 0, stream>>>(Wl1, Wr1, wlr1_bf);
  k_wlr2_bf<<<(2 * HC * HC + 255) / 256, 256, 0, stream>>>(Wl2, Wr2, wlr2_bf);
  k_wp_bf<<<(EMB * HC + 255) / 256, 256, 0, stream>>>(Wp, wp_bf);
  k_pack_static<<<(N_NODES * DS + 255) / 256, 256, 0, stream>>>(x_static, packG1);
  k_pack_dyn<<<(N_NODES * DD + 255) / 256, 256, 0, stream>>>(dyn, packXH);
  k_deg<<<(EP + 255) / 256, 256, 0, stream>>>(ei, deg);
  k_scan<<<1, 1024, 0, stream>>>(deg, rowstart);
  k_fill<<<(EP + 255) / 256, 256, 0, stream>>>(ei, rowstart, cursor, csr);

  const int GY = MP / 128;                       // 160 (divisible by 8)

  for (int t = 0; t < T_SEQ; ++t) {
    // ---- LSTM step t ----
    gemm_mfma<<<4 * GY, 256, 0, stream>>>(packXH, KP1, wcat_bf, KP1, bsum,
                                          gates, HC, MP, HC, KP1, 0, 2);
    lstm_update<<<(N_NODES * HL + 255) / 256, 256, 0, stream>>>(
        gates, c, packXH, packG1, dyn, t + 1);

    hipMemsetAsync(stats, 0, 4 * HC * sizeof(float), stream);

    // ---- GAT layer 1 ----
    gemm_mfma<<<8 * GY, 256, 0, stream>>>(packG1, KP1, wlr1_bf, KP1, nullptr,
                                          xlr, 1024, MP, 2 * HC, KP1, 1, 3);
    gat_edge<<<N_NODES / 4, 256, 0, stream>>>(xlr, att1, bg1, rowstart, csr, gout);
    bn_stats<<<500, 256, 0, stream>>>(gout, stats);
    bn_apply<<<(N_NODES * HC / 2 + 255) / 256, 256, 0, stream>>>(gout, stats,
                                                                 gamma1, beta1, aggb);

    // ---- GAT layer 2 ----
    gemm_mfma<<<8 * GY, 256, 0, stream>>>(aggb, HC, wlr2_bf, HC, nullptr,
                                          xlr, 1024, MP, 2 * HC, HC, 1, 3);
    gat_edge<<<N_NODES / 4, 256, 0, stream>>>(xlr, att2, bg2, rowstart, csr, gout);
    bn_stats<<<500, 256, 0, stream>>>(gout, stats + 2 * HC);
    bn_apply<<<(N_NODES * HC / 2 + 255) / 256, 256, 0, stream>>>(gout, stats + 2 * HC,
                                                                 gamma2, beta2, aggb);

    // ---- output projection into out[n][t][:] ----
    gemm_mfma<<<1 * GY, 256, 0, stream>>>(aggb, HC, wp_bf, HC, bp,
                                          out + t * EMB, T_SEQ * EMB,
                                          N_NODES, EMB, HC, 0, 0);
  }
}

// Round 7
// 2455.155 us; speedup vs baseline: 3.0578x; 1.0186x over previous
//
#include <hip/hip_runtime.h>
#include <math.h>

typedef unsigned short u16;
typedef unsigned int u32;

#define N_NODES 20000
#define MP      20480            // N padded to multiple of 1024 (128 x 8 XCD groups)
#define T_SEQ   8
#define DS      16
#define DD      8
#define E_EDGES 320000
#define HL      128
#define GH      4
#define GC      128
#define HC      512
#define EMB     64
#define KP1     160              // padded K for LSTM (136) and GAT1 (144)
#define EP      (E_EDGES + N_NODES)
#define EPP     (EP + 3 * N_NODES)   // CSR rows padded to multiple of 4

typedef __attribute__((ext_vector_type(8))) short bf16x8;
typedef __attribute__((ext_vector_type(4))) float f32x4;

__device__ __forceinline__ u16 f2bf(float f) {
  u32 u = __float_as_uint(f);
  u += 0x7fff + ((u >> 16) & 1);   // RNE (inputs are finite)
  return (u16)(u >> 16);
}
__device__ __forceinline__ float bflo(u32 v) { return __uint_as_float(v << 16); }
__device__ __forceinline__ float bfhi(u32 v) { return __uint_as_float(v & 0xffff0000u); }
__device__ __forceinline__ float bf16f(u16 v) { return __uint_as_float((u32)v << 16); }

__device__ __forceinline__ void gld16(const void* g, void* l) {
  __builtin_amdgcn_global_load_lds(
      (const __attribute__((address_space(1))) void*)g,
      (__attribute__((address_space(3))) void*)l, 16, 0, 0);
}

// sum across each 16-lane row via DPP row_ror (pure VALU, no LDS pipe)
__device__ __forceinline__ float rowsum16(float p) {
  p += __int_as_float(__builtin_amdgcn_update_dpp(0, __float_as_int(p), 0x121, 0xf, 0xf, false));
  p += __int_as_float(__builtin_amdgcn_update_dpp(0, __float_as_int(p), 0x122, 0xf, 0xf, false));
  p += __int_as_float(__builtin_amdgcn_update_dpp(0, __float_as_int(p), 0x124, 0xf, 0xf, false));
  p += __int_as_float(__builtin_amdgcn_update_dpp(0, __float_as_int(p), 0x128, 0xf, 0xf, false));
  return p;
}

// ---------------------------------------------------------------------------
// bf16 MFMA GEMM: C[M,Nc] = A[M,K] @ W[Nc,K]^T (+bias).
// 128x128 tile, BK=32, double-buffered LDS (prefetch-after-barrier).
// XCD-aware swizzle (id%8 -> XCD); bf16 out via LDS-staged coalesced epilogue.
// ---------------------------------------------------------------------------
__global__ __launch_bounds__(256) void gemm_mfma(
    const u16* __restrict__ A, int lda,
    const u16* __restrict__ W, int ldw,
    const float* __restrict__ bias,
    void* __restrict__ Cout, int ldc,
    int M, int Nc, int K, int c_bf16, int gxs)
{
  __shared__ u16 smem[16384];            // dbuf staging; epilogue: C tile
  u16* Asm = smem;
  u16* Bsm = smem + 8192;

  const int tid = threadIdx.x;
  const int wave = tid >> 6, lane = tid & 63;
  const int wm = (wave >> 1) << 6, wn = (wave & 1) << 6;

  const u32 id = blockIdx.x;
  const int xcd = id & 7;
  const u32 sl = id >> 3;
  const int GXm = (1 << gxs) - 1;
  const int bn = (int)(sl & GXm) << 7;
  const int bm = (xcd + (int)((sl >> gxs) << 3)) << 7;

  f32x4 acc[4][4];
#pragma unroll
  for (int i = 0; i < 4; ++i)
#pragma unroll
    for (int j = 0; j < 4; ++j) acc[i][j] = (f32x4){0.f, 0.f, 0.f, 0.f};

  const int qr = lane >> 2;
  const int qc = (lane & 3) << 3;
  const int q0 = wave * 2, q1 = wave * 2 + 1;
  const int ra0 = bm + q0 * 16 + qr;
  const int ra1 = bm + q1 * 16 + qr;
  int rb0 = bn + q0 * 16 + qr; if (rb0 >= Nc) rb0 = Nc - 1;
  int rb1 = bn + q1 * 16 + qr; if (rb1 >= Nc) rb1 = Nc - 1;

  const u16* pa0 = A + (size_t)ra0 * lda + qc;
  const u16* pa1 = A + (size_t)ra1 * lda + qc;
  const u16* pb0 = W + (size_t)rb0 * ldw + qc;
  const u16* pb1 = W + (size_t)rb1 * ldw + qc;

  const int fm = lane & 15;
  const int fk = (lane >> 4) << 3;

  gld16(pa0, &Asm[q0 * 512]);
  gld16(pa1, &Asm[q1 * 512]);
  gld16(pb0, &Bsm[q0 * 512]);
  gld16(pb1, &Bsm[q1 * 512]);
  pa0 += 32; pa1 += 32; pb0 += 32; pb1 += 32;

  const int iters = K >> 5;
#pragma unroll 2
  for (int it = 0; it < iters; ++it) {
    const int cur = (it & 1) * 4096;
    __syncthreads();
    if (it + 1 < iters) {
      const int nxt = cur ^ 4096;
      gld16(pa0, &Asm[nxt + q0 * 512]);
      gld16(pa1, &Asm[nxt + q1 * 512]);
      gld16(pb0, &Bsm[nxt + q0 * 512]);
      gld16(pb1, &Bsm[nxt + q1 * 512]);
      pa0 += 32; pa1 += 32; pb0 += 32; pb1 += 32;
    }
    bf16x8 af[4], bfr[4];
#pragma unroll
    for (int i = 0; i < 4; ++i)
      af[i] = *(const bf16x8*)&Asm[cur + (wm + i * 16 + fm) * 32 + fk];
#pragma unroll
    for (int j = 0; j < 4; ++j)
      bfr[j] = *(const bf16x8*)&Bsm[cur + (wn + j * 16 + fm) * 32 + fk];
#pragma unroll
    for (int i = 0; i < 4; ++i)
#pragma unroll
      for (int j = 0; j < 4; ++j)
        acc[i][j] = __builtin_amdgcn_mfma_f32_16x16x32_bf16(af[i], bfr[j], acc[i][j], 0, 0, 0);
  }

  const int cn = lane & 15, cm = (lane >> 4) << 2;
  if (c_bf16) {
    __syncthreads();
#pragma unroll
    for (int j = 0; j < 4; ++j) {
      const int c = wn + j * 16 + cn;
      const float bb = bias ? bias[bn + c] : 0.f;
#pragma unroll
      for (int i = 0; i < 4; ++i) {
#pragma unroll
        for (int r = 0; r < 4; ++r)
          smem[(wm + i * 16 + cm + r) * 128 + c] = f2bf(acc[i][j][r] + bb);
      }
    }
    __syncthreads();
    u16* outc = (u16*)Cout;
#pragma unroll
    for (int k = 0; k < 8; ++k) {
      const int idx = tid + k * 256;
      const int r = idx >> 4, cc = (idx & 15) << 3;
      *(uint4*)(outc + (size_t)(bm + r) * ldc + bn + cc) = *(const uint4*)&smem[r * 128 + cc];
    }
  } else {
#pragma unroll
    for (int j = 0; j < 4; ++j) {
      const int c = bn + wn + j * 16 + cn;
      if (c >= Nc) continue;
      const float bb = bias ? bias[c] : 0.f;
#pragma unroll
      for (int i = 0; i < 4; ++i) {
#pragma unroll
        for (int r = 0; r < 4; ++r) {
          const int m = bm + wm + i * 16 + cm + r;
          if (m >= M) continue;
          ((float*)Cout)[(size_t)m * ldc + c] = acc[i][j][r] + bb;
        }
      }
    }
  }
}

// ---------------------------------------------------------------------------
// Setup / conversion kernels (once per launch; tiny)
// ---------------------------------------------------------------------------
__global__ void k_bias_sum(const float* __restrict__ b_ih,
                           const float* __restrict__ b_hh,
                           float* __restrict__ bsum) {
  int i = blockIdx.x * blockDim.x + threadIdx.x;
  if (i < 4 * HL) bsum[i] = b_ih[i] + b_hh[i];
}

__global__ void k_wcat_bf(const float* __restrict__ W_ih,
                          const float* __restrict__ W_hh,
                          u16* __restrict__ w) {
  int idx = blockIdx.x * blockDim.x + threadIdx.x;
  if (idx >= HC * KP1) return;
  int j = idx / KP1, k = idx - j * KP1;
  float v = 0.f;
  if (k < DD) v = W_ih[j * DD + k];
  else if (k < DD + HL) v = W_hh[j * HL + (k - DD)];
  w[idx] = f2bf(v);
}

__global__ void k_wlr1_bf(const float* __restrict__ Wl,
                          const float* __restrict__ Wr,
                          u16* __restrict__ w) {
  int idx = blockIdx.x * blockDim.x + threadIdx.x;
  if (idx >= 2 * HC * KP1) return;
  int j = idx / KP1, k = idx - j * KP1;
  const float* src = (j < HC) ? Wl : Wr;
  int jj = j & (HC - 1);
  float v = (k < DS + HL) ? src[jj * (DS + HL) + k] : 0.f;
  w[idx] = f2bf(v);
}

__global__ void k_wlr2_bf(const float* __restrict__ Wl,
                          const float* __restrict__ Wr,
                          u16* __restrict__ w) {
  int idx = blockIdx.x * blockDim.x + threadIdx.x;
  if (idx >= 2 * HC * HC) return;
  int j = idx >> 9, k = idx & (HC - 1);
  const float* src = (j < HC) ? Wl : Wr;
  int jj = j & (HC - 1);
  w[idx] = f2bf(src[jj * HC + k]);
}

__global__ void k_wp_bf(const float* __restrict__ Wp, u16* __restrict__ w) {
  int idx = blockIdx.x * blockDim.x + threadIdx.x;
  if (idx < EMB * HC) w[idx] = f2bf(Wp[idx]);
}

__global__ void k_pack_static(const float* __restrict__ xs, u16* __restrict__ packG1) {
  int idx = blockIdx.x * blockDim.x + threadIdx.x;
  if (idx >= N_NODES * DS) return;
  int n = idx >> 4, k = idx & 15;
  packG1[(size_t)n * KP1 + k] = f2bf(xs[idx]);
}

__global__ void k_pack_dyn(const float* __restrict__ dyn, u16* __restrict__ packXH) {
  int idx = blockIdx.x * blockDim.x + threadIdx.x;
  if (idx >= N_NODES * DD) return;
  int n = idx >> 3, k = idx & 7;
  packXH[(size_t)n * KP1 + k] = f2bf(dyn[(size_t)n * (T_SEQ * DD) + k]);
}

// LSTM pointwise; gates in bf16; writes h into both GEMM inputs + next dyn cols
__global__ void lstm_update(const u16* __restrict__ gatesb,
                            float* __restrict__ c,
                            u16* __restrict__ packXH, u16* __restrict__ packG1,
                            const float* __restrict__ dyn, int t_next) {
  int idx = blockIdx.x * blockDim.x + threadIdx.x;
  if (idx >= N_NODES * HL) return;
  int n = idx >> 7, j = idx & 127;
  const u16* g = gatesb + (size_t)n * HC;
  float gi = bf16f(g[j]), gf = bf16f(g[j + 128]);
  float gg = bf16f(g[j + 256]), go = bf16f(g[j + 384]);
  float si = 1.f / (1.f + __expf(-gi));
  float sf = 1.f / (1.f + __expf(-gf));
  float so = 1.f / (1.f + __expf(-go));
  float cn = sf * c[idx] + si * tanhf(gg);
  c[idx] = cn;
  u16 hb = f2bf(so * tanhf(cn));
  packXH[(size_t)n * KP1 + DD + j] = hb;
  packG1[(size_t)n * KP1 + DS + j] = hb;
  if (j < DD && t_next < T_SEQ)
    packXH[(size_t)n * KP1 + j] =
        f2bf(dyn[(size_t)n * (T_SEQ * DD) + t_next * DD + j]);
}

// ---------------------------------------------------------------------------
// CSR build (dst-sorted, rows padded to multiple of 4), rebuilt every launch.
// Entries stored pre-shifted: real = s<<11, pad = (d<<11)|1 (w forced to 0).
// ---------------------------------------------------------------------------
__global__ void k_deg(const int* __restrict__ ei, int* __restrict__ deg) {
  int e = blockIdx.x * blockDim.x + threadIdx.x;
  if (e >= EP) return;
  int d = (e < E_EDGES) ? ei[E_EDGES + e] : (e - E_EDGES);
  atomicAdd(&deg[d], 1);
}

__global__ __launch_bounds__(1024) void k_scan(const int* __restrict__ deg,
                                               int* __restrict__ rowstart) {
  __shared__ int buf[1024];
  __shared__ int carry_s;
  const int tid = threadIdx.x;
  if (tid == 0) carry_s = 0;
  __syncthreads();
  for (int base = 0; base < N_NODES; base += 1024) {
    int v = (base + tid < N_NODES) ? ((deg[base + tid] + 3) & ~3) : 0;  // padded
    buf[tid] = v;
    __syncthreads();
    for (int off = 1; off < 1024; off <<= 1) {
      int add = (tid >= off) ? buf[tid - off] : 0;
      __syncthreads();
      buf[tid] += add;
      __syncthreads();
    }
    int incl = buf[tid];
    int carry = carry_s;
    if (base + tid < N_NODES) rowstart[base + tid] = carry + incl - v;
    __syncthreads();
    if (tid == 1023) carry_s = carry + incl;
    __syncthreads();
  }
  if (tid == 0) rowstart[N_NODES] = carry_s;
}

__global__ void k_fill(const int* __restrict__ ei,
                       const int* __restrict__ rowstart,
                       int* __restrict__ cursor, u32* __restrict__ csr) {
  int e = blockIdx.x * blockDim.x + threadIdx.x;
  if (e >= EP) return;
  int s, d;
  if (e < E_EDGES) { s = ei[e]; d = ei[E_EDGES + e]; }
  else             { s = d = e - E_EDGES; }
  int pos = atomicAdd(&cursor[d], 1);
  csr[rowstart[d] + pos] = (u32)s << 11;
}

__global__ void k_pad(const int* __restrict__ deg,
                      const int* __restrict__ rowstart, u32* __restrict__ csr) {
  int d = blockIdx.x * blockDim.x + threadIdx.x;
  if (d >= N_NODES) return;
  int s = rowstart[d] + deg[d], e = rowstart[d + 1];
  const u32 pv = ((u32)d << 11) | 1;
  for (int i = s; i < e; ++i) csr[i] = pv;
}

// ---------------------------------------------------------------------------
// GATv2 edge softmax + aggregation v6. xlr bf16 [MP,1024] (xl | xr).
// One wave per dst; lane = 8 channels (uint4 gather); heads = 16-lane rows.
// Rows are uniform quads (padded, tag bit0 -> w=0); explicit next-quad
// prefetch keeps 8 gathers in flight. DPP reduce; leaky via 0.6*s + 0.4*|s|.
// ---------------------------------------------------------------------------
__global__ __launch_bounds__(256) void gat_edge(
    const u16* __restrict__ xlr,
    const float* __restrict__ att, const float* __restrict__ bias,
    const int* __restrict__ rowstart, const u32* __restrict__ csr,
    u16* __restrict__ outb)
{
  const int wave = threadIdx.x >> 6, lane = threadIdx.x & 63;
  const int d = blockIdx.x * 4 + wave;
  const int ch = lane * 8;                  // [0,512); head = lane>>4
  const uint4 vr = *(const uint4*)(xlr + (size_t)d * 1024 + 512 + ch);
  const float rxa0 = bflo(vr.x), rxa1 = bfhi(vr.x), rxa2 = bflo(vr.y), rxa3 = bfhi(vr.y);
  const float rxb0 = bflo(vr.z), rxb1 = bfhi(vr.z), rxb2 = bflo(vr.w), rxb3 = bfhi(vr.w);
  const float4 ava = *(const float4*)(att + ch);
  const float4 avb = *(const float4*)(att + ch + 4);
  const int row = rowstart[d], end = rowstart[d + 1];
  const char* __restrict__ xbase = (const char*)(xlr + ch);  // + (s<<11) bytes

  float l = 0.f;
  float a0 = 0.f, a1 = 0.f, a2 = 0.f, a3 = 0.f;
  float b0 = 0.f, b1 = 0.f, b2 = 0.f, b3 = 0.f;

#define GLD(o) (*(const uint4*)(xbase + (size_t)((o) & ~1u)))

#define GAT_STEP(v, o)                                                       \
  {                                                                          \
    const float xa0 = bflo((v).x), xa1 = bfhi((v).x);                        \
    const float xa2 = bflo((v).y), xa3 = bfhi((v).y);                        \
    const float xb0 = bflo((v).z), xb1 = bfhi((v).z);                        \
    const float xb2 = bflo((v).w), xb3 = bfhi((v).w);                        \
    const float e0 = xa0 + rxa0, e1 = xa1 + rxa1;                            \
    const float e2 = xa2 + rxa2, e3 = xa3 + rxa3;                            \
    const float f0 = xb0 + rxb0, f1 = xb1 + rxb1;                            \
    const float f2 = xb2 + rxb2, f3 = xb3 + rxb3;                            \
    float ps = e0 * ava.x;                                                   \
    ps = fmaf(e1, ava.y, ps); ps = fmaf(e2, ava.z, ps);                      \
    ps = fmaf(e3, ava.w, ps); ps = fmaf(f0, avb.x, ps);                      \
    ps = fmaf(f1, avb.y, ps); ps = fmaf(f2, avb.z, ps);                      \
    ps = fmaf(f3, avb.w, ps);                                                \
    float pa = fabsf(e0) * ava.x;                                            \
    pa = fmaf(fabsf(e1), ava.y, pa); pa = fmaf(fabsf(e2), ava.z, pa);        \
    pa = fmaf(fabsf(e3), ava.w, pa); pa = fmaf(fabsf(f0), avb.x, pa);        \
    pa = fmaf(fabsf(f1), avb.y, pa); pa = fmaf(fabsf(f2), avb.z, pa);        \
    pa = fmaf(fabsf(f3), avb.w, pa);                                         \
    float p = rowsum16(fmaf(0.6f, ps, 0.4f * pa));                           \
    float w = __expf(p);                                                     \
    w = ((o) & 1) ? 0.f : w;                                                 \
    l += w;                                                                  \
    a0 = fmaf(w, xa0, a0); a1 = fmaf(w, xa1, a1);                            \
    a2 = fmaf(w, xa2, a2); a3 = fmaf(w, xa3, a3);                            \
    b0 = fmaf(w, xb0, b0); b1 = fmaf(w, xb1, b1);                            \
    b2 = fmaf(w, xb2, b2); b3 = fmaf(w, xb3, b3);                            \
  }

  const u32* cp = csr + row;
  const int nq = (end - row) >> 2;       // >= 1 (self-loop guaranteed)

  u32 o0 = cp[0], o1 = cp[1], o2 = cp[2], o3 = cp[3];
  uint4 v0 = GLD(o0), v1 = GLD(o1), v2 = GLD(o2), v3 = GLD(o3);

  for (int q = 1; q < nq; ++q) {
    cp += 4;
    const u32 n0 = cp[0], n1 = cp[1], n2 = cp[2], n3 = cp[3];
    const uint4 w0 = GLD(n0), w1 = GLD(n1), w2 = GLD(n2), w3 = GLD(n3);
    GAT_STEP(v0, o0);
    GAT_STEP(v1, o1);
    GAT_STEP(v2, o2);
    GAT_STEP(v3, o3);
    o0 = n0; o1 = n1; o2 = n2; o3 = n3;
    v0 = w0; v1 = w1; v2 = w2; v3 = w3;
  }
  GAT_STEP(v0, o0);
  GAT_STEP(v1, o1);
  GAT_STEP(v2, o2);
  GAT_STEP(v3, o3);
#undef GAT_STEP
#undef GLD

  const float inv = 1.f / l;
  const float4 ba = *(const float4*)(bias + ch);
  const float4 bb = *(const float4*)(bias + ch + 4);
  uint4 ov;
  ov.x = (u32)f2bf(fmaf(a0, inv, ba.x)) | ((u32)f2bf(fmaf(a1, inv, ba.y)) << 16);
  ov.y = (u32)f2bf(fmaf(a2, inv, ba.z)) | ((u32)f2bf(fmaf(a3, inv, ba.w)) << 16);
  ov.z = (u32)f2bf(fmaf(b0, inv, bb.x)) | ((u32)f2bf(fmaf(b1, inv, bb.y)) << 16);
  ov.w = (u32)f2bf(fmaf(b2, inv, bb.z)) | ((u32)f2bf(fmaf(b3, inv, bb.w)) << 16);
  *(uint4*)(outb + (size_t)d * HC + ch) = ov;
}

// ---------------------------------------------------------------------------
// BatchNorm stats (bf16 input): stats[0..HC)=sum, [HC..2HC)=sumsq
// ---------------------------------------------------------------------------
__global__ __launch_bounds__(256) void bn_stats(const u16* __restrict__ x,
                                                float* __restrict__ stats) {
  const int tid = threadIdx.x;
  const int rows_per = (N_NODES + gridDim.x - 1) / gridDim.x;
  const int r0 = blockIdx.x * rows_per;
  const int r1 = min(r0 + rows_per, N_NODES);
  const u32* xp = (const u32*)x;
  float s0 = 0.f, s1 = 0.f, q0 = 0.f, q1 = 0.f;
  for (int r = r0; r < r1; ++r) {
    const u32 v = xp[(size_t)r * 256 + tid];
    const float v0 = bflo(v), v1 = bfhi(v);
    s0 += v0; q0 += v0 * v0;
    s1 += v1; q1 += v1 * v1;
  }
  atomicAdd(&stats[2 * tid],          s0);
  atomicAdd(&stats[2 * tid + 1],      s1);
  atomicAdd(&stats[HC + 2 * tid],     q0);
  atomicAdd(&stats[HC + 2 * tid + 1], q1);
}

__global__ void bn_apply(const u16* __restrict__ x, const float* __restrict__ stats,
                         const float* __restrict__ gamma, const float* __restrict__ beta,
                         u16* __restrict__ outb) {
  int idx = blockIdx.x * blockDim.x + threadIdx.x;
  if (idx >= N_NODES * (HC / 2)) return;
  const int cc = idx & (HC / 2 - 1);
  const int c0 = cc * 2, c1 = c0 + 1;
  const u32 v = ((const u32*)x)[idx];
  const float mean0 = stats[c0] * (1.f / N_NODES);
  const float mean1 = stats[c1] * (1.f / N_NODES);
  const float inv0 = rsqrtf(stats[HC + c0] * (1.f / N_NODES) - mean0 * mean0 + 1e-5f);
  const float inv1 = rsqrtf(stats[HC + c1] * (1.f / N_NODES) - mean1 * mean1 + 1e-5f);
  float z0 = (bflo(v) - mean0) * inv0 * gamma[c0] + beta[c0];
  float z1 = (bfhi(v) - mean1) * inv1 * gamma[c1] + beta[c1];
  z0 = z0 > 0.f ? z0 : 0.f;
  z1 = z1 > 0.f ? z1 : 0.f;
  ((u32*)outb)[idx] = (u32)f2bf(z0) | ((u32)f2bf(z1) << 16);
}

// ---------------------------------------------------------------------------
extern "C" void kernel_launch(void* const* d_in, const int* in_sizes, int n_in,
                              void* d_out, int out_size, void* d_ws, size_t ws_size,
                              hipStream_t stream) {
  const float* x_static = (const float*)d_in[0];
  const float* dyn      = (const float*)d_in[1];
  const int*   ei       = (const int*)d_in[2];
  const float* W_ih     = (const float*)d_in[3];
  const float* W_hh     = (const float*)d_in[4];
  const float* b_ih     = (const float*)d_in[5];
  const float* b_hh     = (const float*)d_in[6];
  const float* Wl1      = (const float*)d_in[7];
  const float* Wr1      = (const float*)d_in[8];
  const float* att1     = (const float*)d_in[9];
  const float* bg1      = (const float*)d_in[10];
  const float* Wl2      = (const float*)d_in[11];
  const float* Wr2      = (const float*)d_in[12];
  const float* att2     = (const float*)d_in[13];
  const float* bg2      = (const float*)d_in[14];
  const float* gamma1   = (const float*)d_in[15];
  const float* beta1    = (const float*)d_in[16];
  const float* gamma2   = (const float*)d_in[17];
  const float* beta2    = (const float*)d_in[18];
  const float* Wp       = (const float*)d_in[19];
  const float* bp       = (const float*)d_in[20];
  float* out = (float*)d_out;

  // ---- workspace carve (float units) ----
  float* ws = (float*)d_ws;
  size_t o = 0;
  float* c        = ws + o; o += (size_t)MP * HL;
  float* statsAll = ws + o; o += (size_t)T_SEQ * 4 * HC;
  float* bsum     = ws + o; o += 4 * HL;
  u16* gatesb  = (u16*)(ws + o); o += (size_t)MP * HC / 2;
  u16* packXH  = (u16*)(ws + o); o += (size_t)MP * KP1 / 2;
  u16* packG1  = (u16*)(ws + o); o += (size_t)MP * KP1 / 2;
  u16* xlr     = (u16*)(ws + o); o += (size_t)MP * 1024 / 2;
  u16* gout    = (u16*)(ws + o); o += (size_t)MP * HC / 2;
  u16* aggb    = (u16*)(ws + o); o += (size_t)MP * HC / 2;
  u16* wcat_bf = (u16*)(ws + o); o += (size_t)HC * KP1 / 2;
  u16* wlr1_bf = (u16*)(ws + o); o += (size_t)2 * HC * KP1 / 2;
  u16* wlr2_bf = (u16*)(ws + o); o += (size_t)2 * HC * HC / 2;
  u16* wp_bf   = (u16*)(ws + o); o += (size_t)EMB * HC / 2;
  int* deg      = (int*)(ws + o); o += N_NODES;
  int* cursor   = (int*)(ws + o); o += N_NODES;
  int* rowstart = (int*)(ws + o); o += N_NODES + 64;
  u32* csr      = (u32*)(ws + o); o += EPP;

  // ---- per-launch init ----
  hipMemsetAsync(deg,      0, N_NODES * sizeof(int), stream);
  hipMemsetAsync(cursor,   0, N_NODES * sizeof(int), stream);
  hipMemsetAsync(statsAll, 0, (size_t)T_SEQ * 4 * HC * sizeof(float), stream);
  hipMemsetAsync(c,        0, (size_t)MP * HL * sizeof(float), stream);
  hipMemsetAsync(packXH,   0, (size_t)MP * KP1 * sizeof(u16), stream);  // h=0 + pads
  hipMemsetAsync(packG1,   0, (size_t)MP * KP1 * sizeof(u16), stream);
  hipMemsetAsync(aggb,     0, (size_t)MP * HC * sizeof(u16), stream);   // pad rows

  k_bias_sum<<<2, 256, 0, stream>>>(b_ih, b_hh, bsum);
  k_wcat_bf<<<(HC * KP1 + 255) / 256, 256, 0, stream>>>(W_ih, W_hh, wcat_bf);
  k_wlr1_bf<<<(2 * HC * KP1 + 255) / 256, 256, 0, stream>>>(Wl1, Wr1, wlr1_bf);
  k_wlr2_bf<<<(2 * HC * HC + 255) / 256, 256, 0, stream>>>(Wl2, Wr2, wlr2_bf);
  k_wp_bf<<<(EMB * HC + 255) / 256, 256, 0, stream>>>(Wp, wp_bf);
  k_pack_static<<<(N_NODES * DS + 255) / 256, 256, 0, stream>>>(x_static, packG1);
  k_pack_dyn<<<(N_NODES * DD + 255) / 256, 256, 0, stream>>>(dyn, packXH);
  k_deg<<<(EP + 255) / 256, 256, 0, stream>>>(ei, deg);
  k_scan<<<1, 1024, 0, stream>>>(deg, rowstart);
  k_fill<<<(EP + 255) / 256, 256, 0, stream>>>(ei, rowstart, cursor, csr);
  k_pad<<<(N_NODES + 255) / 256, 256, 0, stream>>>(deg, rowstart, csr);

  const int GY = MP / 128;                       // 160 (divisible by 8)

  for (int t = 0; t < T_SEQ; ++t) {
    float* stats = statsAll + (size_t)t * 4 * HC;

    // ---- LSTM step t ----
    gemm_mfma<<<4 * GY, 256, 0, stream>>>(packXH, KP1, wcat_bf, KP1, bsum,
                                          gatesb, HC, MP, HC, KP1, 1, 2);
    lstm_update<<<(N_NODES * HL + 255) / 256, 256, 0, stream>>>(
        gatesb, c, packXH, packG1, dyn, t + 1);

    // ---- GAT layer 1 ----
    gemm_mfma<<<8 * GY, 256, 0, stream>>>(packG1, KP1, wlr1_bf, KP1, nullptr,
                                          xlr, 1024, MP, 2 * HC, KP1, 1, 3);
    gat_edge<<<N_NODES / 4, 256, 0, stream>>>(xlr, att1, bg1, rowstart, csr, gout);
    bn_stats<<<500, 256, 0, stream>>>(gout, stats);
    bn_apply<<<(N_NODES * HC / 2 + 255) / 256, 256, 0, stream>>>(gout, stats,
                                                                 gamma1, beta1, aggb);

    // ---- GAT layer 2 ----
    gemm_mfma<<<8 * GY, 256, 0, stream>>>(aggb, HC, wlr2_bf, HC, nullptr,
                                          xlr, 1024, MP, 2 * HC, HC, 1, 3);
    gat_edge<<<N_NODES / 4, 256, 0, stream>>>(xlr, att2, bg2, rowstart, csr, gout);
    bn_stats<<<500, 256, 0, stream>>>(gout, stats + 2 * HC);
    bn_apply<<<(N_NODES * HC / 2 + 255) / 256, 256, 0, stream>>>(gout, stats + 2 * HC,
                                                                 gamma2, beta2, aggb);

    // ---- output projection into out[n][t][:] ----
    gemm_mfma<<<1 * GY, 256, 0, stream>>>(aggb, HC, wp_bf, HC, bp,
                                          out + t * EMB, T_SEQ * EMB,
                                          N_NODES, EMB, HC, 0, 0);
  }
}